// Round 6
// baseline (301.877 us; speedup 1.0000x reference)
//
#include <hip/hip_runtime.h>

typedef float f32x4 __attribute__((ext_vector_type(4)));
typedef __bf16 bf16x8 __attribute__((ext_vector_type(8)));

__device__ __forceinline__ unsigned short f2bf(float f) {
    union { float f; unsigned u; } v; v.f = f;
    unsigned r = v.u + 0x7fffu + ((v.u >> 16) & 1u);
    return (unsigned short)(r >> 16);
}

#define AS1 __attribute__((address_space(1)))
#define AS3 __attribute__((address_space(3)))
// async 16B/lane global->LDS
__device__ __forceinline__ void async16(const void* g, void* l) {
    __builtin_amdgcn_global_load_lds((AS1 void*)g, (AS3 void*)l, 16, 0, 0);
}

// CK-style barrier: orders LDS only (lgkmcnt), leaves global loads (vmcnt) in flight.
__device__ __forceinline__ void sync_lds() {
    asm volatile("s_waitcnt lgkmcnt(0)\n\ts_barrier" ::: "memory");
}

// XOR swizzle for 32-col (4-group) rows
#define SWZ4(r) ((((r) & 3) ^ (((r) >> 2) & 3)))

// ---------------- weight transpose + bf16 convert: W[K][N] -> Wt[N][K] ----------------
__global__ void transpose_cvt(const float* __restrict__ W, unsigned short* __restrict__ Wt,
                              int K, int N) {
    __shared__ float tile[32][33];
    int n0 = blockIdx.x * 32, k0 = blockIdx.y * 32;
    int tx = threadIdx.x, ty = threadIdx.y;
#pragma unroll
    for (int i = 0; i < 32; i += 8)
        tile[ty + i][tx] = W[(size_t)(k0 + ty + i) * N + n0 + tx];
    __syncthreads();
#pragma unroll
    for (int i = 0; i < 32; i += 8)
        Wt[(size_t)(n0 + ty + i) * K + k0 + tx] = f2bf(tile[tx][ty + i]);
}

// ---------------- LayerNorm (ddof=1, /(std+eps)), fp32 in -> bf16 out ----------------
__global__ __launch_bounds__(256) void ln_kernel(const float* __restrict__ x,
                                                 unsigned short* __restrict__ t,
                                                 const float* __restrict__ alpha,
                                                 const float* __restrict__ bias) {
    const int row = blockIdx.x;
    const float* xr = x + (size_t)row * 768;
    float v[3], sum = 0.f, ss = 0.f;
#pragma unroll
    for (int i = 0; i < 3; i++) {
        v[i] = xr[threadIdx.x + 256 * i];
        sum += v[i]; ss += v[i] * v[i];
    }
#pragma unroll
    for (int off = 32; off; off >>= 1) {
        sum += __shfl_down(sum, off);
        ss  += __shfl_down(ss, off);
    }
    __shared__ float s1[4], s2[4];
    int wid = threadIdx.x >> 6, lane = threadIdx.x & 63;
    if (lane == 0) { s1[wid] = sum; s2[wid] = ss; }
    __syncthreads();
    if (threadIdx.x == 0) {
        float a = 0.f, b = 0.f;
#pragma unroll
        for (int i = 0; i < 4; i++) { a += s1[i]; b += s2[i]; }
        s1[0] = a; s2[0] = b;
    }
    __syncthreads();
    sum = s1[0]; ss = s2[0];
    float mean = sum * (1.f / 768.f);
    float var = (ss - sum * mean) * (1.f / 767.f);   // unbiased (ddof=1)
    float sc = alpha[0] / (sqrtf(fmaxf(var, 0.f)) + 1e-6f);
    float bs = bias[0];
#pragma unroll
    for (int i = 0; i < 3; i++)
        t[(size_t)row * 768 + threadIdx.x + 256 * i] = f2bf(sc * (v[i] - mean) + bs);
}

// ---------------- GEMM 128x128, register-prefetch pipelined, BK=32 --------------------
// MODE 0: out bf16 = v              MODE 1: out bf16 = relu(v + bias[col])
// MODE 2: out f32 = v + res         MODE 3: out f32 = v + bias[col] + res
template <int MODE>
__global__ __launch_bounds__(256, 3) void gemm_bt(
    const unsigned short* __restrict__ A, const unsigned short* __restrict__ Bt,
    int M, int N, int K, const float* __restrict__ bias,
    const float* __restrict__ res, void* __restrict__ outp) {
    __shared__ __align__(16) unsigned short As[2][128 * 32];
    __shared__ __align__(16) unsigned short Bs[2][128 * 32];
    const int tid = threadIdx.x;
    const int lane = tid & 63, w = tid >> 6;
    const int wm = w & 1, wn = w >> 1;
    const int m0 = blockIdx.y * 128, n0 = blockIdx.x * 128;
    const int quad = lane >> 4, l16 = lane & 15;

    const int r0 = tid >> 2, g0 = tid & 3;           // rows 0..63
    const int r1 = r0 + 64, g1 = g0;                 // rows 64..127
    const unsigned short* gA0 = A  + (size_t)(m0 + r0) * K + g0 * 8;
    const unsigned short* gA1 = A  + (size_t)(m0 + r1) * K + g1 * 8;
    const unsigned short* gB0 = Bt + (size_t)(n0 + r0) * K + g0 * 8;
    const unsigned short* gB1 = Bt + (size_t)(n0 + r1) * K + g1 * 8;
    const int wA0 = r0 * 32 + ((g0 ^ SWZ4(r0)) * 8);
    const int wA1 = r1 * 32 + ((g1 ^ SWZ4(r1)) * 8);

    f32x4 acc[4][4];
    const f32x4 z = {0.f, 0.f, 0.f, 0.f};
#pragma unroll
    for (int mt = 0; mt < 4; mt++)
#pragma unroll
        for (int nt = 0; nt < 4; nt++) acc[mt][nt] = z;

    bf16x8 ra0 = *(const bf16x8*)gA0, ra1 = *(const bf16x8*)gA1;
    bf16x8 rb0 = *(const bf16x8*)gB0, rb1 = *(const bf16x8*)gB1;
    gA0 += 32; gA1 += 32; gB0 += 32; gB1 += 32;

    const int nK = K >> 5;
    for (int kt = 0; kt < nK; ++kt) {
        unsigned short* Ac = As[kt & 1];
        unsigned short* Bc = Bs[kt & 1];
        *(bf16x8*)&Ac[wA0] = ra0; *(bf16x8*)&Ac[wA1] = ra1;
        *(bf16x8*)&Bc[wA0] = rb0; *(bf16x8*)&Bc[wA1] = rb1;
        if (kt + 1 < nK) {
            ra0 = *(const bf16x8*)gA0; ra1 = *(const bf16x8*)gA1;
            rb0 = *(const bf16x8*)gB0; rb1 = *(const bf16x8*)gB1;
            gA0 += 32; gA1 += 32; gB0 += 32; gB1 += 32;
        }
        sync_lds();
        bf16x8 af[4], bf[4];
#pragma unroll
        for (int mt = 0; mt < 4; mt++) {
            int r = 64 * wm + 16 * mt + l16;
            af[mt] = *(const bf16x8*)&Ac[r * 32 + ((quad ^ SWZ4(r)) * 8)];
        }
#pragma unroll
        for (int nt = 0; nt < 4; nt++) {
            int r = 64 * wn + 16 * nt + l16;
            bf[nt] = *(const bf16x8*)&Bc[r * 32 + ((quad ^ SWZ4(r)) * 8)];
        }
#pragma unroll
        for (int mt = 0; mt < 4; mt++)
#pragma unroll
            for (int nt = 0; nt < 4; nt++)
                acc[mt][nt] = __builtin_amdgcn_mfma_f32_16x16x32_bf16(af[mt], bf[nt], acc[mt][nt], 0, 0, 0);
    }

#pragma unroll
    for (int mt = 0; mt < 4; mt++) {
#pragma unroll
        for (int nt = 0; nt < 4; nt++) {
            const int col = n0 + 64 * wn + 16 * nt + l16;
            float bv = 0.f;
            if (MODE == 1 || MODE == 3) bv = bias[col];
#pragma unroll
            for (int r = 0; r < 4; r++) {
                const int row = m0 + 64 * wm + 16 * mt + quad * 4 + r;
                const size_t idx = (size_t)row * N + col;
                const float v = acc[mt][nt][r];
                if (MODE == 0) ((unsigned short*)outp)[idx] = f2bf(v);
                else if (MODE == 1) ((unsigned short*)outp)[idx] = f2bf(fmaxf(v + bv, 0.f));
                else if (MODE == 2) ((float*)outp)[idx] = v + res[idx];
                else ((float*)outp)[idx] = v + bv + res[idx];
            }
        }
    }
}

// ---------------- GEMM 64x64, register-prefetch pipelined, BK=64 ----------------------
template <int MODE>
__global__ __launch_bounds__(256, 3) void gemm64_bt(
    const unsigned short* __restrict__ A, const unsigned short* __restrict__ Bt,
    int M, int N, int K, const float* __restrict__ bias,
    const float* __restrict__ res, void* __restrict__ outp) {
    __shared__ __align__(16) unsigned short As[2][64 * 64];
    __shared__ __align__(16) unsigned short Bs[2][64 * 64];
    const int tid = threadIdx.x;
    const int lane = tid & 63, w = tid >> 6;
    const int m0 = blockIdx.y * 64, n0 = blockIdx.x * 64;
    const int quad = lane >> 4, l16 = lane & 15;

    const int r0 = tid >> 3, g0 = tid & 7;           // rows 0..31
    const int r1 = r0 + 32, g1 = g0;                 // rows 32..63
    const unsigned short* gA0 = A  + (size_t)(m0 + r0) * K + g0 * 8;
    const unsigned short* gA1 = A  + (size_t)(m0 + r1) * K + g1 * 8;
    const unsigned short* gB0 = Bt + (size_t)(n0 + r0) * K + g0 * 8;
    const unsigned short* gB1 = Bt + (size_t)(n0 + r1) * K + g1 * 8;
    const int wA0 = r0 * 64 + ((g0 ^ (r0 & 7)) * 8);
    const int wA1 = r1 * 64 + ((g1 ^ (r1 & 7)) * 8);

    f32x4 acc[4];
    const f32x4 z = {0.f, 0.f, 0.f, 0.f};
#pragma unroll
    for (int nt = 0; nt < 4; nt++) acc[nt] = z;

    bf16x8 ra0 = *(const bf16x8*)gA0, ra1 = *(const bf16x8*)gA1;
    bf16x8 rb0 = *(const bf16x8*)gB0, rb1 = *(const bf16x8*)gB1;
    gA0 += 64; gA1 += 64; gB0 += 64; gB1 += 64;

    const int nK = K >> 6;
    for (int kt = 0; kt < nK; ++kt) {
        unsigned short* Ac = As[kt & 1];
        unsigned short* Bc = Bs[kt & 1];
        *(bf16x8*)&Ac[wA0] = ra0; *(bf16x8*)&Ac[wA1] = ra1;
        *(bf16x8*)&Bc[wA0] = rb0; *(bf16x8*)&Bc[wA1] = rb1;
        if (kt + 1 < nK) {
            ra0 = *(const bf16x8*)gA0; ra1 = *(const bf16x8*)gA1;
            rb0 = *(const bf16x8*)gB0; rb1 = *(const bf16x8*)gB1;
            gA0 += 64; gA1 += 64; gB0 += 64; gB1 += 64;
        }
        sync_lds();
        const int ra = 16 * w + l16;
        bf16x8 af0 = *(const bf16x8*)&Ac[ra * 64 + (((0 + quad) ^ (ra & 7)) * 8)];
        bf16x8 af1 = *(const bf16x8*)&Ac[ra * 64 + (((4 + quad) ^ (ra & 7)) * 8)];
#pragma unroll
        for (int nt = 0; nt < 4; nt++) {
            int rb = 16 * nt + l16;
            bf16x8 bf0 = *(const bf16x8*)&Bc[rb * 64 + (((0 + quad) ^ (rb & 7)) * 8)];
            bf16x8 bf1 = *(const bf16x8*)&Bc[rb * 64 + (((4 + quad) ^ (rb & 7)) * 8)];
            acc[nt] = __builtin_amdgcn_mfma_f32_16x16x32_bf16(af0, bf0, acc[nt], 0, 0, 0);
            acc[nt] = __builtin_amdgcn_mfma_f32_16x16x32_bf16(af1, bf1, acc[nt], 0, 0, 0);
        }
    }

#pragma unroll
    for (int nt = 0; nt < 4; nt++) {
        const int col = n0 + 16 * nt + l16;
        float bv = 0.f;
        if (MODE == 1 || MODE == 3) bv = bias[col];
#pragma unroll
        for (int rr = 0; rr < 4; rr++) {
            const int row = m0 + 16 * w + quad * 4 + rr;
            const size_t idx = (size_t)row * N + col;
            const float v = acc[nt][rr];
            if (MODE == 0) ((unsigned short*)outp)[idx] = f2bf(v);
            else if (MODE == 1) ((unsigned short*)outp)[idx] = f2bf(fmaxf(v + bv, 0.f));
            else if (MODE == 2) ((float*)outp)[idx] = v + res[idx];
            else ((float*)outp)[idx] = v + bv + res[idx];
        }
    }
}

// ---------------- V transpose: qkv[.,1536+h*64+dd] -> vt[bh][dd][S] ----------------
__global__ void v_transpose(const unsigned short* __restrict__ qkvc,
                            unsigned short* __restrict__ vt) {
    __shared__ unsigned short t[64][65];
    const int bh = blockIdx.y, b = bh / 12, h = bh % 12;
    const int s0 = blockIdx.x * 64;
    const int tx = threadIdx.x, ty = threadIdx.y;   // 64 x 4
#pragma unroll
    for (int i = 0; i < 64; i += 4)
        t[ty + i][tx] = qkvc[(size_t)(b * 2048 + s0 + ty + i) * 2304 + 1536 + h * 64 + tx];
    __syncthreads();
#pragma unroll
    for (int i = 0; i < 64; i += 4)
        vt[((size_t)bh * 64 + ty + i) * 2048 + s0 + tx] = t[tx][ty + i];
}

// ---------------- flash attention v4: k-split waves, partial-O reduction --------------
// LDS-bound fix: each wave owns a 32-wide k-chunk of the 128 K-tile and computes
// S/P for ALL 64 q-rows on that chunk. K/V B-frag LDS reads amortize over 64 rows:
// 36 -> 12 ds_read_b128 per wave-iter. No online max => k-split is embarrassingly
// parallel: per-wave partial O_w/L_w accumulators, one LDS reduction at the end.
__global__ __launch_bounds__(256, 3) void flash_attn(
    const unsigned short* __restrict__ qkvc,   // [4096][2304] fused q|k|v
    const unsigned short* __restrict__ vt,     // [24][64][2048]
    const int* __restrict__ mask,              // [2][2048]
    unsigned short* __restrict__ attno) {      // [4096][768]
    const int bh = blockIdx.y, b = bh / 12, h = bh % 12;
    const int s0 = blockIdx.x * 64;
    __shared__ __align__(16) unsigned short UQP[4 * 64 * 40];  // Qs pre-loop; Ps[w][64][40] in-loop
    __shared__ __align__(16) unsigned short Ks[128 * 64];      // fp32 Osc[4][16][64] in epilogue
    __shared__ __align__(16) unsigned short Vs[64 * 128];      // fp32 Lsc[4][64] in epilogue
    __shared__ int Ms[128];
    const int tid = threadIdx.x, lane = tid & 63, w = tid >> 6;
    const int quad = lane >> 4, l16 = lane & 15;

    // stage Q tile [64 rows][64 cols] (swizzle g^(r&7))
    {
        int sl0 = (2 * w) * 64 + lane;
        int r0 = sl0 >> 3, g0 = sl0 & 7;
        int sl1 = sl0 + 64;
        int r1 = sl1 >> 3, g1 = sl1 & 7;
        async16(qkvc + (size_t)(b * 2048 + s0 + r0) * 2304 + h * 64 + ((g0 ^ (r0 & 7)) * 8),
                UQP + (2 * w) * 512);
        async16(qkvc + (size_t)(b * 2048 + s0 + r1) * 2304 + h * 64 + ((g1 ^ (r1 & 7)) * 8),
                UQP + (2 * w + 1) * 512);
    }
    __syncthreads();
    // every wave holds Q A-frags for ALL 64 q-rows (4 row-blocks x K=64 dims)
    bf16x8 aQ[4][2];
#pragma unroll
    for (int mt = 0; mt < 4; mt++) {
        int r = 16 * mt + l16;
#pragma unroll
        for (int kk = 0; kk < 2; kk++)
            aQ[mt][kk] = *(const bf16x8*)&UQP[r * 64 + (((kk * 4 + quad) ^ (r & 7)) * 8)];
    }
    __bf16* Ps = (__bf16*)UQP + w * (64 * 40);   // wave-local, rows 16B-aligned (stride 40)

    f32x4 Oacc[4][4], Lacc[4];
    const f32x4 z = {0.f, 0.f, 0.f, 0.f};
#pragma unroll
    for (int mt = 0; mt < 4; mt++) {
        Lacc[mt] = z;
#pragma unroll
        for (int nt = 0; nt < 4; nt++) Oacc[mt][nt] = z;
    }
    bf16x8 ones;
#pragma unroll
    for (int i = 0; i < 8; i++) ones[i] = (__bf16)1.0f;

    const unsigned short* kbase = qkvc + 768;
    const unsigned short* vbase = vt + (size_t)bh * 64 * 2048;
    const float SCL = 0.125f * 1.44269504088896340736f;   // 1/sqrt(64) * log2(e)
    const float MSK = 1.4426950408889634e-9f;             // 1e-9 * log2(e)

    for (int j = 0; j < 16; j++) {
        const int k0 = j * 128;
        __syncthreads();
#pragma unroll
        for (int c = 0; c < 4; c++) {
            int sl = (4 * w + c) * 64 + lane;
            int r = sl >> 3, g = sl & 7;
            async16(kbase + (size_t)(b * 2048 + k0 + r) * 2304 + h * 64 + ((g ^ (r & 7)) * 8),
                    Ks + (4 * w + c) * 512);
        }
#pragma unroll
        for (int c = 0; c < 4; c++) {
            int sl = (4 * w + c) * 64 + lane;
            int r = sl >> 4, g = sl & 15;
            async16(vbase + (size_t)r * 2048 + k0 + ((g ^ (r & 15)) * 8),
                    Vs + (4 * w + c) * 512);
        }
        if (tid < 128) Ms[tid] = mask[b * 2048 + k0 + tid];
        __syncthreads();

        // S[64 q][32 k]: this wave's chunk = k-cols [w*32, w*32+32)
        f32x4 sc[4][2];
#pragma unroll
        for (int nt = 0; nt < 2; nt++) {
            const int rr = w * 32 + nt * 16 + l16;
            bf16x8 bk0 = *(const bf16x8*)&Ks[rr * 64 + (((0 + quad) ^ (rr & 7)) * 8)];
            bf16x8 bk1 = *(const bf16x8*)&Ks[rr * 64 + (((4 + quad) ^ (rr & 7)) * 8)];
#pragma unroll
            for (int mt = 0; mt < 4; mt++) {
                f32x4 t0 = __builtin_amdgcn_mfma_f32_16x16x32_bf16(aQ[mt][0], bk0, z, 0, 0, 0);
                sc[mt][nt] = __builtin_amdgcn_mfma_f32_16x16x32_bf16(aQ[mt][1], bk1, t0, 0, 0, 0);
            }
        }
        // p = exp(s/8) with mask quirk (masked: s := 1e-9)
#pragma unroll
        for (int nt = 0; nt < 2; nt++) {
            const int msk = Ms[w * 32 + nt * 16 + l16];
            const float fs = msk ? SCL : 0.f;
            const float ad = msk ? 0.f : MSK;
#pragma unroll
            for (int mt = 0; mt < 4; mt++)
#pragma unroll
                for (int r = 0; r < 4; r++)
                    sc[mt][nt][r] = __builtin_amdgcn_exp2f(fmaf(sc[mt][nt][r], fs, ad));
        }
        // P: C-layout -> wave-local LDS [64 q][stride 40]
#pragma unroll
        for (int mt = 0; mt < 4; mt++)
#pragma unroll
            for (int nt = 0; nt < 2; nt++)
#pragma unroll
                for (int r = 0; r < 4; r++)
                    Ps[(mt * 16 + quad * 4 + r) * 40 + nt * 16 + l16] = (__bf16)sc[mt][nt][r];

        // O_w += P_w V[chunk] ; L_w += P_w 1   (partial over this wave's 32 k)
#pragma unroll
        for (int mt = 0; mt < 4; mt++) {
            bf16x8 aP = *(const bf16x8*)&Ps[(mt * 16 + l16) * 40 + quad * 8];
            Lacc[mt] = __builtin_amdgcn_mfma_f32_16x16x32_bf16(aP, ones, Lacc[mt], 0, 0, 0);
#pragma unroll
            for (int nt = 0; nt < 4; nt++) {
                const int rr = nt * 16 + l16;
                bf16x8 bv = *(const bf16x8*)&Vs[rr * 128 + (((w * 4 + quad) ^ (rr & 15)) * 8)];
                Oacc[mt][nt] = __builtin_amdgcn_mfma_f32_16x16x32_bf16(aP, bv, Oacc[mt][nt], 0, 0, 0);
            }
        }
    }

    // ---- cross-wave reduction of O/L partials (one-time) ----
    __syncthreads();
    float* Osc = (float*)Ks;   // [4 waves][16 rows][64 cols]
    float* Lsc = (float*)Vs;   // [4 waves][64 rows]
    if (l16 == 0) {
#pragma unroll
        for (int mt = 0; mt < 4; mt++)
#pragma unroll
            for (int r = 0; r < 4; r++)
                Lsc[w * 64 + mt * 16 + quad * 4 + r] = Lacc[mt][r];
    }
#pragma unroll
    for (int mt = 0; mt < 4; mt++) {
#pragma unroll
        for (int nt = 0; nt < 4; nt++)
#pragma unroll
            for (int r = 0; r < 4; r++)
                Osc[(w * 16 + quad * 4 + r) * 64 + nt * 16 + l16] = Oacc[mt][nt][r];
        __syncthreads();
#pragma unroll
        for (int r2 = 0; r2 < 4; r2++) {
            const int lrow = w * 4 + r2;
            float s = Osc[lrow * 64 + lane] + Osc[1024 + lrow * 64 + lane]
                    + Osc[2048 + lrow * 64 + lane] + Osc[3072 + lrow * 64 + lane];
            float L = Lsc[mt * 16 + lrow] + Lsc[64 + mt * 16 + lrow]
                    + Lsc[128 + mt * 16 + lrow] + Lsc[192 + mt * 16 + lrow];
            const int row = s0 + mt * 16 + lrow;
            attno[(size_t)(b * 2048 + row) * 768 + h * 64 + lane] = f2bf(s / L);
        }
        __syncthreads();
    }
}

// =====================================================================================
extern "C" void kernel_launch(void* const* d_in, const int* in_sizes, int n_in,
                              void* d_out, int out_size, void* d_ws, size_t ws_size,
                              hipStream_t stream) {
    const float* x    = (const float*)d_in[0];
    const int*   mask = (const int*)d_in[1];
    const float* wq   = (const float*)d_in[2];
    const float* wk   = (const float*)d_in[3];
    const float* wv   = (const float*)d_in[4];
    const float* wo   = (const float*)d_in[5];
    const float* w1   = (const float*)d_in[6];
    const float* b1   = (const float*)d_in[7];
    const float* w2   = (const float*)d_in[8];
    const float* b2   = (const float*)d_in[9];
    const float* ln1a = (const float*)d_in[10];
    const float* ln1b = (const float*)d_in[11];
    const float* ln2a = (const float*)d_in[12];
    const float* ln2b = (const float*)d_in[13];

    char* p = (char*)d_ws;
    auto carve = [&](size_t bytes) {
        char* q = p;
        p += (bytes + 255) & ~(size_t)255;
        return q;
    };
    unsigned short* wTqkv = (unsigned short*)carve((size_t)2304 * 768 * 2);
    unsigned short* wTo   = (unsigned short*)carve((size_t)768 * 768 * 2);
    unsigned short* wT1   = (unsigned short*)carve((size_t)3072 * 768 * 2);
    unsigned short* wT2   = (unsigned short*)carve((size_t)768 * 3072 * 2);
    unsigned short* vtb   = (unsigned short*)carve((size_t)24 * 64 * 2048 * 2);
    float*          x1    = (float*)carve((size_t)4096 * 768 * 4);
    char* unionA = carve((size_t)4096 * 768 * 2 + (size_t)4096 * 2304 * 2);
    unsigned short* t1   = (unsigned short*)unionA;
    unsigned short* qkvc = (unsigned short*)(unionA + (size_t)4096 * 768 * 2);
    unsigned short* ffnh = (unsigned short*)unionA;
    unsigned short* attno = (unsigned short*)carve((size_t)4096 * 768 * 2);
    unsigned short* t2 = attno;

    dim3 tb(32, 8);
    transpose_cvt<<<dim3(24, 24), tb, 0, stream>>>(wq, wTqkv, 768, 768);
    transpose_cvt<<<dim3(24, 24), tb, 0, stream>>>(wk, wTqkv + (size_t)768 * 768, 768, 768);
    transpose_cvt<<<dim3(24, 24), tb, 0, stream>>>(wv, wTqkv + (size_t)1536 * 768, 768, 768);
    transpose_cvt<<<dim3(24, 24), tb, 0, stream>>>(wo, wTo, 768, 768);
    transpose_cvt<<<dim3(96, 24), tb, 0, stream>>>(w1, wT1, 768, 3072);
    transpose_cvt<<<dim3(24, 96), tb, 0, stream>>>(w2, wT2, 3072, 768);

    ln_kernel<<<4096, 256, 0, stream>>>(x, t1, ln1a, ln1b);
    gemm_bt<0><<<dim3(18, 32), 256, 0, stream>>>(t1, wTqkv, 4096, 2304, 768,
                                                 nullptr, nullptr, qkvc);
    v_transpose<<<dim3(32, 24), dim3(64, 4), 0, stream>>>(qkvc, vtb);
    flash_attn<<<dim3(32, 24), 256, 0, stream>>>(qkvc, vtb, mask, attno);
    gemm64_bt<2><<<dim3(12, 64), 256, 0, stream>>>(attno, wTo, 4096, 768, 768,
                                                   nullptr, x, x1);
    ln_kernel<<<4096, 256, 0, stream>>>(x1, t2, ln2a, ln2b);
    gemm_bt<1><<<dim3(24, 32), 256, 0, stream>>>(t2, wT1, 4096, 3072, 768,
                                                 b1, nullptr, ffnh);
    gemm64_bt<3><<<dim3(12, 64), 256, 0, stream>>>(ffnh, wT2, 4096, 768, 3072,
                                                   b2, x1, (float*)d_out);
}

// Round 7
// 291.810 us; speedup vs baseline: 1.0345x; 1.0345x over previous
//
#include <hip/hip_runtime.h>

typedef float f32x4 __attribute__((ext_vector_type(4)));
typedef __bf16 bf16x8 __attribute__((ext_vector_type(8)));

__device__ __forceinline__ unsigned short f2bf(float f) {
    union { float f; unsigned u; } v; v.f = f;
    unsigned r = v.u + 0x7fffu + ((v.u >> 16) & 1u);
    return (unsigned short)(r >> 16);
}

#define AS1 __attribute__((address_space(1)))
#define AS3 __attribute__((address_space(3)))
// async 16B/lane global->LDS
__device__ __forceinline__ void async16(const void* g, void* l) {
    __builtin_amdgcn_global_load_lds((AS1 void*)g, (AS3 void*)l, 16, 0, 0);
}

// CK-style barrier: orders LDS only (lgkmcnt), leaves global loads (vmcnt) in flight.
__device__ __forceinline__ void sync_lds() {
    asm volatile("s_waitcnt lgkmcnt(0)\n\ts_barrier" ::: "memory");
}

// XOR swizzle for 32-col (4-group) rows
#define SWZ4(r) ((((r) & 3) ^ (((r) >> 2) & 3)))

// ---------------- weight transpose + bf16 convert: W[K][N] -> Wt[N][K] ----------------
__global__ void transpose_cvt(const float* __restrict__ W, unsigned short* __restrict__ Wt,
                              int K, int N) {
    __shared__ float tile[32][33];
    int n0 = blockIdx.x * 32, k0 = blockIdx.y * 32;
    int tx = threadIdx.x, ty = threadIdx.y;
#pragma unroll
    for (int i = 0; i < 32; i += 8)
        tile[ty + i][tx] = W[(size_t)(k0 + ty + i) * N + n0 + tx];
    __syncthreads();
#pragma unroll
    for (int i = 0; i < 32; i += 8)
        Wt[(size_t)(n0 + ty + i) * K + k0 + tx] = f2bf(tile[tx][ty + i]);
}

// ---------------- LayerNorm (ddof=1, /(std+eps)), fp32 in -> bf16 out ----------------
__global__ __launch_bounds__(256) void ln_kernel(const float* __restrict__ x,
                                                 unsigned short* __restrict__ t,
                                                 const float* __restrict__ alpha,
                                                 const float* __restrict__ bias) {
    const int row = blockIdx.x;
    const float* xr = x + (size_t)row * 768;
    float v[3], sum = 0.f, ss = 0.f;
#pragma unroll
    for (int i = 0; i < 3; i++) {
        v[i] = xr[threadIdx.x + 256 * i];
        sum += v[i]; ss += v[i] * v[i];
    }
#pragma unroll
    for (int off = 32; off; off >>= 1) {
        sum += __shfl_down(sum, off);
        ss  += __shfl_down(ss, off);
    }
    __shared__ float s1[4], s2[4];
    int wid = threadIdx.x >> 6, lane = threadIdx.x & 63;
    if (lane == 0) { s1[wid] = sum; s2[wid] = ss; }
    __syncthreads();
    if (threadIdx.x == 0) {
        float a = 0.f, b = 0.f;
#pragma unroll
        for (int i = 0; i < 4; i++) { a += s1[i]; b += s2[i]; }
        s1[0] = a; s2[0] = b;
    }
    __syncthreads();
    sum = s1[0]; ss = s2[0];
    float mean = sum * (1.f / 768.f);
    float var = (ss - sum * mean) * (1.f / 767.f);   // unbiased (ddof=1)
    float sc = alpha[0] / (sqrtf(fmaxf(var, 0.f)) + 1e-6f);
    float bs = bias[0];
#pragma unroll
    for (int i = 0; i < 3; i++)
        t[(size_t)row * 768 + threadIdx.x + 256 * i] = f2bf(sc * (v[i] - mean) + bs);
}

// ---------------- GEMM 128x128, register-prefetch pipelined, BK=32 --------------------
// MODE 0: out bf16 = v              MODE 1: out bf16 = relu(v + bias[col])
// MODE 2: out f32 = v + res         MODE 3: out f32 = v + bias[col] + res
template <int MODE>
__global__ __launch_bounds__(256, 3) void gemm_bt(
    const unsigned short* __restrict__ A, const unsigned short* __restrict__ Bt,
    int M, int N, int K, const float* __restrict__ bias,
    const float* __restrict__ res, void* __restrict__ outp) {
    __shared__ __align__(16) unsigned short As[2][128 * 32];
    __shared__ __align__(16) unsigned short Bs[2][128 * 32];
    const int tid = threadIdx.x;
    const int lane = tid & 63, w = tid >> 6;
    const int wm = w & 1, wn = w >> 1;
    const int m0 = blockIdx.y * 128, n0 = blockIdx.x * 128;
    const int quad = lane >> 4, l16 = lane & 15;

    const int r0 = tid >> 2, g0 = tid & 3;           // rows 0..63
    const int r1 = r0 + 64, g1 = g0;                 // rows 64..127
    const unsigned short* gA0 = A  + (size_t)(m0 + r0) * K + g0 * 8;
    const unsigned short* gA1 = A  + (size_t)(m0 + r1) * K + g1 * 8;
    const unsigned short* gB0 = Bt + (size_t)(n0 + r0) * K + g0 * 8;
    const unsigned short* gB1 = Bt + (size_t)(n0 + r1) * K + g1 * 8;
    const int wA0 = r0 * 32 + ((g0 ^ SWZ4(r0)) * 8);
    const int wA1 = r1 * 32 + ((g1 ^ SWZ4(r1)) * 8);

    f32x4 acc[4][4];
    const f32x4 z = {0.f, 0.f, 0.f, 0.f};
#pragma unroll
    for (int mt = 0; mt < 4; mt++)
#pragma unroll
        for (int nt = 0; nt < 4; nt++) acc[mt][nt] = z;

    bf16x8 ra0 = *(const bf16x8*)gA0, ra1 = *(const bf16x8*)gA1;
    bf16x8 rb0 = *(const bf16x8*)gB0, rb1 = *(const bf16x8*)gB1;
    gA0 += 32; gA1 += 32; gB0 += 32; gB1 += 32;

    const int nK = K >> 5;
    for (int kt = 0; kt < nK; ++kt) {
        unsigned short* Ac = As[kt & 1];
        unsigned short* Bc = Bs[kt & 1];
        *(bf16x8*)&Ac[wA0] = ra0; *(bf16x8*)&Ac[wA1] = ra1;
        *(bf16x8*)&Bc[wA0] = rb0; *(bf16x8*)&Bc[wA1] = rb1;
        if (kt + 1 < nK) {
            ra0 = *(const bf16x8*)gA0; ra1 = *(const bf16x8*)gA1;
            rb0 = *(const bf16x8*)gB0; rb1 = *(const bf16x8*)gB1;
            gA0 += 32; gA1 += 32; gB0 += 32; gB1 += 32;
        }
        sync_lds();
        bf16x8 af[4], bf[4];
#pragma unroll
        for (int mt = 0; mt < 4; mt++) {
            int r = 64 * wm + 16 * mt + l16;
            af[mt] = *(const bf16x8*)&Ac[r * 32 + ((quad ^ SWZ4(r)) * 8)];
        }
#pragma unroll
        for (int nt = 0; nt < 4; nt++) {
            int r = 64 * wn + 16 * nt + l16;
            bf[nt] = *(const bf16x8*)&Bc[r * 32 + ((quad ^ SWZ4(r)) * 8)];
        }
#pragma unroll
        for (int mt = 0; mt < 4; mt++)
#pragma unroll
            for (int nt = 0; nt < 4; nt++)
                acc[mt][nt] = __builtin_amdgcn_mfma_f32_16x16x32_bf16(af[mt], bf[nt], acc[mt][nt], 0, 0, 0);
    }

#pragma unroll
    for (int mt = 0; mt < 4; mt++) {
#pragma unroll
        for (int nt = 0; nt < 4; nt++) {
            const int col = n0 + 64 * wn + 16 * nt + l16;
            float bv = 0.f;
            if (MODE == 1 || MODE == 3) bv = bias[col];
#pragma unroll
            for (int r = 0; r < 4; r++) {
                const int row = m0 + 64 * wm + 16 * mt + quad * 4 + r;
                const size_t idx = (size_t)row * N + col;
                const float v = acc[mt][nt][r];
                if (MODE == 0) ((unsigned short*)outp)[idx] = f2bf(v);
                else if (MODE == 1) ((unsigned short*)outp)[idx] = f2bf(fmaxf(v + bv, 0.f));
                else if (MODE == 2) ((float*)outp)[idx] = v + res[idx];
                else ((float*)outp)[idx] = v + bv + res[idx];
            }
        }
    }
}

// ---------------- GEMM 64x64, register-prefetch pipelined, BK=64 ----------------------
template <int MODE>
__global__ __launch_bounds__(256, 3) void gemm64_bt(
    const unsigned short* __restrict__ A, const unsigned short* __restrict__ Bt,
    int M, int N, int K, const float* __restrict__ bias,
    const float* __restrict__ res, void* __restrict__ outp) {
    __shared__ __align__(16) unsigned short As[2][64 * 64];
    __shared__ __align__(16) unsigned short Bs[2][64 * 64];
    const int tid = threadIdx.x;
    const int lane = tid & 63, w = tid >> 6;
    const int m0 = blockIdx.y * 64, n0 = blockIdx.x * 64;
    const int quad = lane >> 4, l16 = lane & 15;

    const int r0 = tid >> 3, g0 = tid & 7;           // rows 0..31
    const int r1 = r0 + 32, g1 = g0;                 // rows 32..63
    const unsigned short* gA0 = A  + (size_t)(m0 + r0) * K + g0 * 8;
    const unsigned short* gA1 = A  + (size_t)(m0 + r1) * K + g1 * 8;
    const unsigned short* gB0 = Bt + (size_t)(n0 + r0) * K + g0 * 8;
    const unsigned short* gB1 = Bt + (size_t)(n0 + r1) * K + g1 * 8;
    const int wA0 = r0 * 64 + ((g0 ^ (r0 & 7)) * 8);
    const int wA1 = r1 * 64 + ((g1 ^ (r1 & 7)) * 8);

    f32x4 acc[4];
    const f32x4 z = {0.f, 0.f, 0.f, 0.f};
#pragma unroll
    for (int nt = 0; nt < 4; nt++) acc[nt] = z;

    bf16x8 ra0 = *(const bf16x8*)gA0, ra1 = *(const bf16x8*)gA1;
    bf16x8 rb0 = *(const bf16x8*)gB0, rb1 = *(const bf16x8*)gB1;
    gA0 += 64; gA1 += 64; gB0 += 64; gB1 += 64;

    const int nK = K >> 6;
    for (int kt = 0; kt < nK; ++kt) {
        unsigned short* Ac = As[kt & 1];
        unsigned short* Bc = Bs[kt & 1];
        *(bf16x8*)&Ac[wA0] = ra0; *(bf16x8*)&Ac[wA1] = ra1;
        *(bf16x8*)&Bc[wA0] = rb0; *(bf16x8*)&Bc[wA1] = rb1;
        if (kt + 1 < nK) {
            ra0 = *(const bf16x8*)gA0; ra1 = *(const bf16x8*)gA1;
            rb0 = *(const bf16x8*)gB0; rb1 = *(const bf16x8*)gB1;
            gA0 += 64; gA1 += 64; gB0 += 64; gB1 += 64;
        }
        sync_lds();
        const int ra = 16 * w + l16;
        bf16x8 af0 = *(const bf16x8*)&Ac[ra * 64 + (((0 + quad) ^ (ra & 7)) * 8)];
        bf16x8 af1 = *(const bf16x8*)&Ac[ra * 64 + (((4 + quad) ^ (ra & 7)) * 8)];
#pragma unroll
        for (int nt = 0; nt < 4; nt++) {
            int rb = 16 * nt + l16;
            bf16x8 bf0 = *(const bf16x8*)&Bc[rb * 64 + (((0 + quad) ^ (rb & 7)) * 8)];
            bf16x8 bf1 = *(const bf16x8*)&Bc[rb * 64 + (((4 + quad) ^ (rb & 7)) * 8)];
            acc[nt] = __builtin_amdgcn_mfma_f32_16x16x32_bf16(af0, bf0, acc[nt], 0, 0, 0);
            acc[nt] = __builtin_amdgcn_mfma_f32_16x16x32_bf16(af1, bf1, acc[nt], 0, 0, 0);
        }
    }

#pragma unroll
    for (int nt = 0; nt < 4; nt++) {
        const int col = n0 + 16 * nt + l16;
        float bv = 0.f;
        if (MODE == 1 || MODE == 3) bv = bias[col];
#pragma unroll
        for (int rr = 0; rr < 4; rr++) {
            const int row = m0 + 16 * w + quad * 4 + rr;
            const size_t idx = (size_t)row * N + col;
            const float v = acc[nt][rr];
            if (MODE == 0) ((unsigned short*)outp)[idx] = f2bf(v);
            else if (MODE == 1) ((unsigned short*)outp)[idx] = f2bf(fmaxf(v + bv, 0.f));
            else if (MODE == 2) ((float*)outp)[idx] = v + res[idx];
            else ((float*)outp)[idx] = v + bv + res[idx];
        }
    }
}

// ---------------- V transpose: qkv[.,1536+h*64+dd] -> vt[bh][dd][S] ----------------
__global__ void v_transpose(const unsigned short* __restrict__ qkvc,
                            unsigned short* __restrict__ vt) {
    __shared__ unsigned short t[64][65];
    const int bh = blockIdx.y, b = bh / 12, h = bh % 12;
    const int s0 = blockIdx.x * 64;
    const int tx = threadIdx.x, ty = threadIdx.y;   // 64 x 4
#pragma unroll
    for (int i = 0; i < 64; i += 4)
        t[ty + i][tx] = qkvc[(size_t)(b * 2048 + s0 + ty + i) * 2304 + 1536 + h * 64 + tx];
    __syncthreads();
#pragma unroll
    for (int i = 0; i < 64; i += 4)
        vt[((size_t)bh * 64 + ty + i) * 2048 + s0 + tx] = t[tx][ty + i];
}

// ---------------- flash attention v5: k-split waves, spill-free -----------------------
// v4's k-split (K/V LDS-frag reads amortized over all 64 q-rows) but with the register
// pressure fixed: __launch_bounds__(256,2) gives a 256-VGPR budget (v4's (256,3) cap of
// 170 forced ~22MB of scratch spills -> HBM round-trips), and the j-body is restructured
// per-mt so only one sc[2] score block (8 regs) is live at a time.
__global__ __launch_bounds__(256, 2) void flash_attn(
    const unsigned short* __restrict__ qkvc,   // [4096][2304] fused q|k|v
    const unsigned short* __restrict__ vt,     // [24][64][2048]
    const int* __restrict__ mask,              // [2][2048]
    unsigned short* __restrict__ attno) {      // [4096][768]
    const int bh = blockIdx.y, b = bh / 12, h = bh % 12;
    const int s0 = blockIdx.x * 64;
    __shared__ __align__(16) unsigned short UQP[4 * 64 * 40];  // Qs pre-loop; Ps[w][64][40] in-loop
    __shared__ __align__(16) unsigned short Ks[128 * 64];      // fp32 Osc[4][16][64] in epilogue
    __shared__ __align__(16) unsigned short Vs[64 * 128];      // fp32 Lsc[4][64] in epilogue
    __shared__ int Ms[128];
    const int tid = threadIdx.x, lane = tid & 63, w = tid >> 6;
    const int quad = lane >> 4, l16 = lane & 15;

    // stage Q tile [64 rows][64 cols] (swizzle g^(r&7))
    {
        int sl0 = (2 * w) * 64 + lane;
        int r0 = sl0 >> 3, g0 = sl0 & 7;
        int sl1 = sl0 + 64;
        int r1 = sl1 >> 3, g1 = sl1 & 7;
        async16(qkvc + (size_t)(b * 2048 + s0 + r0) * 2304 + h * 64 + ((g0 ^ (r0 & 7)) * 8),
                UQP + (2 * w) * 512);
        async16(qkvc + (size_t)(b * 2048 + s0 + r1) * 2304 + h * 64 + ((g1 ^ (r1 & 7)) * 8),
                UQP + (2 * w + 1) * 512);
    }
    __syncthreads();
    // every wave holds Q A-frags for ALL 64 q-rows (4 row-blocks x K=64 dims)
    bf16x8 aQ[4][2];
#pragma unroll
    for (int mt = 0; mt < 4; mt++) {
        int r = 16 * mt + l16;
#pragma unroll
        for (int kk = 0; kk < 2; kk++)
            aQ[mt][kk] = *(const bf16x8*)&UQP[r * 64 + (((kk * 4 + quad) ^ (r & 7)) * 8)];
    }
    __bf16* Ps = (__bf16*)UQP + w * (64 * 40);   // wave-local, rows 16B-aligned (stride 40)

    f32x4 Oacc[4][4], Lacc[4];
    const f32x4 z = {0.f, 0.f, 0.f, 0.f};
#pragma unroll
    for (int mt = 0; mt < 4; mt++) {
        Lacc[mt] = z;
#pragma unroll
        for (int nt = 0; nt < 4; nt++) Oacc[mt][nt] = z;
    }
    bf16x8 ones;
#pragma unroll
    for (int i = 0; i < 8; i++) ones[i] = (__bf16)1.0f;

    const unsigned short* kbase = qkvc + 768;
    const unsigned short* vbase = vt + (size_t)bh * 64 * 2048;
    const float SCL = 0.125f * 1.44269504088896340736f;   // 1/sqrt(64) * log2(e)
    const float MSK = 1.4426950408889634e-9f;             // 1e-9 * log2(e)

    for (int j = 0; j < 16; j++) {
        const int k0 = j * 128;
        __syncthreads();
#pragma unroll
        for (int c = 0; c < 4; c++) {
            int sl = (4 * w + c) * 64 + lane;
            int r = sl >> 3, g = sl & 7;
            async16(kbase + (size_t)(b * 2048 + k0 + r) * 2304 + h * 64 + ((g ^ (r & 7)) * 8),
                    Ks + (4 * w + c) * 512);
        }
#pragma unroll
        for (int c = 0; c < 4; c++) {
            int sl = (4 * w + c) * 64 + lane;
            int r = sl >> 4, g = sl & 15;
            async16(vbase + (size_t)r * 2048 + k0 + ((g ^ (r & 15)) * 8),
                    Vs + (4 * w + c) * 512);
        }
        if (tid < 128) Ms[tid] = mask[b * 2048 + k0 + tid];
        __syncthreads();

        // this wave's k-chunk = cols [w*32, w*32+32); K-frags read once, reused 4x (mt)
        bf16x8 bk[2][2];
        int mk[2];
#pragma unroll
        for (int nt = 0; nt < 2; nt++) {
            const int rr = w * 32 + nt * 16 + l16;
            bk[nt][0] = *(const bf16x8*)&Ks[rr * 64 + (((0 + quad) ^ (rr & 7)) * 8)];
            bk[nt][1] = *(const bf16x8*)&Ks[rr * 64 + (((4 + quad) ^ (rr & 7)) * 8)];
            mk[nt] = Ms[w * 32 + nt * 16 + l16];
        }
        // per-mt: QK -> exp -> P-write (only 8 score regs live at a time)
#pragma unroll
        for (int mt = 0; mt < 4; mt++) {
#pragma unroll
            for (int nt = 0; nt < 2; nt++) {
                f32x4 t0 = __builtin_amdgcn_mfma_f32_16x16x32_bf16(aQ[mt][0], bk[nt][0], z, 0, 0, 0);
                f32x4 sc = __builtin_amdgcn_mfma_f32_16x16x32_bf16(aQ[mt][1], bk[nt][1], t0, 0, 0, 0);
                const float fs = mk[nt] ? SCL : 0.f;
                const float ad = mk[nt] ? 0.f : MSK;
#pragma unroll
                for (int r = 0; r < 4; r++)
                    Ps[(mt * 16 + quad * 4 + r) * 40 + nt * 16 + l16] =
                        (__bf16)__builtin_amdgcn_exp2f(fmaf(sc[r], fs, ad));
            }
        }
        // V-frags read once, reused 4x (mt)
        bf16x8 bv[4];
#pragma unroll
        for (int nt = 0; nt < 4; nt++) {
            const int rr = nt * 16 + l16;
            bv[nt] = *(const bf16x8*)&Vs[rr * 128 + (((w * 4 + quad) ^ (rr & 15)) * 8)];
        }
        // O_w += P_w V[chunk] ; L_w += P_w 1
#pragma unroll
        for (int mt = 0; mt < 4; mt++) {
            bf16x8 aP = *(const bf16x8*)&Ps[(mt * 16 + l16) * 40 + quad * 8];
            Lacc[mt] = __builtin_amdgcn_mfma_f32_16x16x32_bf16(aP, ones, Lacc[mt], 0, 0, 0);
#pragma unroll
            for (int nt = 0; nt < 4; nt++)
                Oacc[mt][nt] = __builtin_amdgcn_mfma_f32_16x16x32_bf16(aP, bv[nt], Oacc[mt][nt], 0, 0, 0);
        }
    }

    // ---- cross-wave reduction of O/L partials (one-time) ----
    __syncthreads();
    float* Osc = (float*)Ks;   // [4 waves][16 rows][64 cols]
    float* Lsc = (float*)Vs;   // [4 waves][64 rows]
    if (l16 == 0) {
#pragma unroll
        for (int mt = 0; mt < 4; mt++)
#pragma unroll
            for (int r = 0; r < 4; r++)
                Lsc[w * 64 + mt * 16 + quad * 4 + r] = Lacc[mt][r];
    }
#pragma unroll
    for (int mt = 0; mt < 4; mt++) {
#pragma unroll
        for (int nt = 0; nt < 4; nt++)
#pragma unroll
            for (int r = 0; r < 4; r++)
                Osc[(w * 16 + quad * 4 + r) * 64 + nt * 16 + l16] = Oacc[mt][nt][r];
        __syncthreads();
#pragma unroll
        for (int r2 = 0; r2 < 4; r2++) {
            const int lrow = w * 4 + r2;
            float s = Osc[lrow * 64 + lane] + Osc[1024 + lrow * 64 + lane]
                    + Osc[2048 + lrow * 64 + lane] + Osc[3072 + lrow * 64 + lane];
            float L = Lsc[mt * 16 + lrow] + Lsc[64 + mt * 16 + lrow]
                    + Lsc[128 + mt * 16 + lrow] + Lsc[192 + mt * 16 + lrow];
            const int row = s0 + mt * 16 + lrow;
            attno[(size_t)(b * 2048 + row) * 768 + h * 64 + lane] = f2bf(s / L);
        }
        __syncthreads();
    }
}

// =====================================================================================
extern "C" void kernel_launch(void* const* d_in, const int* in_sizes, int n_in,
                              void* d_out, int out_size, void* d_ws, size_t ws_size,
                              hipStream_t stream) {
    const float* x    = (const float*)d_in[0];
    const int*   mask = (const int*)d_in[1];
    const float* wq   = (const float*)d_in[2];
    const float* wk   = (const float*)d_in[3];
    const float* wv   = (const float*)d_in[4];
    const float* wo   = (const float*)d_in[5];
    const float* w1   = (const float*)d_in[6];
    const float* b1   = (const float*)d_in[7];
    const float* w2   = (const float*)d_in[8];
    const float* b2   = (const float*)d_in[9];
    const float* ln1a = (const float*)d_in[10];
    const float* ln1b = (const float*)d_in[11];
    const float* ln2a = (const float*)d_in[12];
    const float* ln2b = (const float*)d_in[13];

    char* p = (char*)d_ws;
    auto carve = [&](size_t bytes) {
        char* q = p;
        p += (bytes + 255) & ~(size_t)255;
        return q;
    };
    unsigned short* wTqkv = (unsigned short*)carve((size_t)2304 * 768 * 2);
    unsigned short* wTo   = (unsigned short*)carve((size_t)768 * 768 * 2);
    unsigned short* wT1   = (unsigned short*)carve((size_t)3072 * 768 * 2);
    unsigned short* wT2   = (unsigned short*)carve((size_t)768 * 3072 * 2);
    unsigned short* vtb   = (unsigned short*)carve((size_t)24 * 64 * 2048 * 2);
    float*          x1    = (float*)carve((size_t)4096 * 768 * 4);
    char* unionA = carve((size_t)4096 * 768 * 2 + (size_t)4096 * 2304 * 2);
    unsigned short* t1   = (unsigned short*)unionA;
    unsigned short* qkvc = (unsigned short*)(unionA + (size_t)4096 * 768 * 2);
    unsigned short* ffnh = (unsigned short*)unionA;
    unsigned short* attno = (unsigned short*)carve((size_t)4096 * 768 * 2);
    unsigned short* t2 = attno;

    dim3 tb(32, 8);
    transpose_cvt<<<dim3(24, 24), tb, 0, stream>>>(wq, wTqkv, 768, 768);
    transpose_cvt<<<dim3(24, 24), tb, 0, stream>>>(wk, wTqkv + (size_t)768 * 768, 768, 768);
    transpose_cvt<<<dim3(24, 24), tb, 0, stream>>>(wv, wTqkv + (size_t)1536 * 768, 768, 768);
    transpose_cvt<<<dim3(24, 24), tb, 0, stream>>>(wo, wTo, 768, 768);
    transpose_cvt<<<dim3(96, 24), tb, 0, stream>>>(w1, wT1, 768, 3072);
    transpose_cvt<<<dim3(24, 96), tb, 0, stream>>>(w2, wT2, 3072, 768);

    ln_kernel<<<4096, 256, 0, stream>>>(x, t1, ln1a, ln1b);
    gemm_bt<0><<<dim3(18, 32), 256, 0, stream>>>(t1, wTqkv, 4096, 2304, 768,
                                                 nullptr, nullptr, qkvc);
    v_transpose<<<dim3(32, 24), dim3(64, 4), 0, stream>>>(qkvc, vtb);
    flash_attn<<<dim3(32, 24), 256, 0, stream>>>(qkvc, vtb, mask, attno);
    gemm64_bt<2><<<dim3(12, 64), 256, 0, stream>>>(attno, wTo, 4096, 768, 768,
                                                   nullptr, x, x1);
    ln_kernel<<<4096, 256, 0, stream>>>(x1, t2, ln2a, ln2b);
    gemm_bt<1><<<dim3(24, 32), 256, 0, stream>>>(t2, wT1, 4096, 3072, 768,
                                                 b1, nullptr, ffnh);
    gemm64_bt<3><<<dim3(12, 64), 256, 0, stream>>>(ffnh, wT2, 4096, 768, 3072,
                                                   b2, x1, (float*)d_out);
}

// Round 8
// 289.677 us; speedup vs baseline: 1.0421x; 1.0074x over previous
//
#include <hip/hip_runtime.h>

typedef float f32x4 __attribute__((ext_vector_type(4)));
typedef __bf16 bf16x8 __attribute__((ext_vector_type(8)));

__device__ __forceinline__ unsigned short f2bf(float f) {
    union { float f; unsigned u; } v; v.f = f;
    unsigned r = v.u + 0x7fffu + ((v.u >> 16) & 1u);
    return (unsigned short)(r >> 16);
}

#define AS1 __attribute__((address_space(1)))
#define AS3 __attribute__((address_space(3)))
// async 16B/lane global->LDS
__device__ __forceinline__ void async16(const void* g, void* l) {
    __builtin_amdgcn_global_load_lds((AS1 void*)g, (AS3 void*)l, 16, 0, 0);
}

// CK-style barrier: orders LDS only (lgkmcnt), leaves global loads (vmcnt) in flight.
__device__ __forceinline__ void sync_lds() {
    asm volatile("s_waitcnt lgkmcnt(0)\n\ts_barrier" ::: "memory");
}

// XOR swizzle for 32-col (4-group) rows
#define SWZ4(r) ((((r) & 3) ^ (((r) >> 2) & 3)))

// ---------------- weight transpose + bf16 convert: W[K][N] -> Wt[N][K] ----------------
__global__ void transpose_cvt(const float* __restrict__ W, unsigned short* __restrict__ Wt,
                              int K, int N) {
    __shared__ float tile[32][33];
    int n0 = blockIdx.x * 32, k0 = blockIdx.y * 32;
    int tx = threadIdx.x, ty = threadIdx.y;
#pragma unroll
    for (int i = 0; i < 32; i += 8)
        tile[ty + i][tx] = W[(size_t)(k0 + ty + i) * N + n0 + tx];
    __syncthreads();
#pragma unroll
    for (int i = 0; i < 32; i += 8)
        Wt[(size_t)(n0 + ty + i) * K + k0 + tx] = f2bf(tile[tx][ty + i]);
}

// ---------------- LayerNorm (ddof=1, /(std+eps)), fp32 in -> bf16 out ----------------
__global__ __launch_bounds__(256) void ln_kernel(const float* __restrict__ x,
                                                 unsigned short* __restrict__ t,
                                                 const float* __restrict__ alpha,
                                                 const float* __restrict__ bias) {
    const int row = blockIdx.x;
    const float* xr = x + (size_t)row * 768;
    float v[3], sum = 0.f, ss = 0.f;
#pragma unroll
    for (int i = 0; i < 3; i++) {
        v[i] = xr[threadIdx.x + 256 * i];
        sum += v[i]; ss += v[i] * v[i];
    }
#pragma unroll
    for (int off = 32; off; off >>= 1) {
        sum += __shfl_down(sum, off);
        ss  += __shfl_down(ss, off);
    }
    __shared__ float s1[4], s2[4];
    int wid = threadIdx.x >> 6, lane = threadIdx.x & 63;
    if (lane == 0) { s1[wid] = sum; s2[wid] = ss; }
    __syncthreads();
    if (threadIdx.x == 0) {
        float a = 0.f, b = 0.f;
#pragma unroll
        for (int i = 0; i < 4; i++) { a += s1[i]; b += s2[i]; }
        s1[0] = a; s2[0] = b;
    }
    __syncthreads();
    sum = s1[0]; ss = s2[0];
    float mean = sum * (1.f / 768.f);
    float var = (ss - sum * mean) * (1.f / 767.f);   // unbiased (ddof=1)
    float sc = alpha[0] / (sqrtf(fmaxf(var, 0.f)) + 1e-6f);
    float bs = bias[0];
#pragma unroll
    for (int i = 0; i < 3; i++)
        t[(size_t)row * 768 + threadIdx.x + 256 * i] = f2bf(sc * (v[i] - mean) + bs);
}

// ---------------- GEMM 128x128, register-prefetch pipelined, BK=32 --------------------
// MODE 0: out bf16 = v              MODE 1: out bf16 = relu(v + bias[col])
// MODE 2: out f32 = v + res         MODE 3: out f32 = v + bias[col] + res
template <int MODE>
__global__ __launch_bounds__(256, 3) void gemm_bt(
    const unsigned short* __restrict__ A, const unsigned short* __restrict__ Bt,
    int M, int N, int K, const float* __restrict__ bias,
    const float* __restrict__ res, void* __restrict__ outp) {
    __shared__ __align__(16) unsigned short As[2][128 * 32];
    __shared__ __align__(16) unsigned short Bs[2][128 * 32];
    const int tid = threadIdx.x;
    const int lane = tid & 63, w = tid >> 6;
    const int wm = w & 1, wn = w >> 1;
    const int m0 = blockIdx.y * 128, n0 = blockIdx.x * 128;
    const int quad = lane >> 4, l16 = lane & 15;

    const int r0 = tid >> 2, g0 = tid & 3;           // rows 0..63
    const int r1 = r0 + 64, g1 = g0;                 // rows 64..127
    const unsigned short* gA0 = A  + (size_t)(m0 + r0) * K + g0 * 8;
    const unsigned short* gA1 = A  + (size_t)(m0 + r1) * K + g1 * 8;
    const unsigned short* gB0 = Bt + (size_t)(n0 + r0) * K + g0 * 8;
    const unsigned short* gB1 = Bt + (size_t)(n0 + r1) * K + g1 * 8;
    const int wA0 = r0 * 32 + ((g0 ^ SWZ4(r0)) * 8);
    const int wA1 = r1 * 32 + ((g1 ^ SWZ4(r1)) * 8);

    f32x4 acc[4][4];
    const f32x4 z = {0.f, 0.f, 0.f, 0.f};
#pragma unroll
    for (int mt = 0; mt < 4; mt++)
#pragma unroll
        for (int nt = 0; nt < 4; nt++) acc[mt][nt] = z;

    bf16x8 ra0 = *(const bf16x8*)gA0, ra1 = *(const bf16x8*)gA1;
    bf16x8 rb0 = *(const bf16x8*)gB0, rb1 = *(const bf16x8*)gB1;
    gA0 += 32; gA1 += 32; gB0 += 32; gB1 += 32;

    const int nK = K >> 5;
    for (int kt = 0; kt < nK; ++kt) {
        unsigned short* Ac = As[kt & 1];
        unsigned short* Bc = Bs[kt & 1];
        *(bf16x8*)&Ac[wA0] = ra0; *(bf16x8*)&Ac[wA1] = ra1;
        *(bf16x8*)&Bc[wA0] = rb0; *(bf16x8*)&Bc[wA1] = rb1;
        if (kt + 1 < nK) {
            ra0 = *(const bf16x8*)gA0; ra1 = *(const bf16x8*)gA1;
            rb0 = *(const bf16x8*)gB0; rb1 = *(const bf16x8*)gB1;
            gA0 += 32; gA1 += 32; gB0 += 32; gB1 += 32;
        }
        sync_lds();
        bf16x8 af[4], bf[4];
#pragma unroll
        for (int mt = 0; mt < 4; mt++) {
            int r = 64 * wm + 16 * mt + l16;
            af[mt] = *(const bf16x8*)&Ac[r * 32 + ((quad ^ SWZ4(r)) * 8)];
        }
#pragma unroll
        for (int nt = 0; nt < 4; nt++) {
            int r = 64 * wn + 16 * nt + l16;
            bf[nt] = *(const bf16x8*)&Bc[r * 32 + ((quad ^ SWZ4(r)) * 8)];
        }
#pragma unroll
        for (int mt = 0; mt < 4; mt++)
#pragma unroll
            for (int nt = 0; nt < 4; nt++)
                acc[mt][nt] = __builtin_amdgcn_mfma_f32_16x16x32_bf16(af[mt], bf[nt], acc[mt][nt], 0, 0, 0);
    }

#pragma unroll
    for (int mt = 0; mt < 4; mt++) {
#pragma unroll
        for (int nt = 0; nt < 4; nt++) {
            const int col = n0 + 64 * wn + 16 * nt + l16;
            float bv = 0.f;
            if (MODE == 1 || MODE == 3) bv = bias[col];
#pragma unroll
            for (int r = 0; r < 4; r++) {
                const int row = m0 + 64 * wm + 16 * mt + quad * 4 + r;
                const size_t idx = (size_t)row * N + col;
                const float v = acc[mt][nt][r];
                if (MODE == 0) ((unsigned short*)outp)[idx] = f2bf(v);
                else if (MODE == 1) ((unsigned short*)outp)[idx] = f2bf(fmaxf(v + bv, 0.f));
                else if (MODE == 2) ((float*)outp)[idx] = v + res[idx];
                else ((float*)outp)[idx] = v + bv + res[idx];
            }
        }
    }
}

// ---------------- GEMM 64x64, register-prefetch pipelined, BK=64 ----------------------
template <int MODE>
__global__ __launch_bounds__(256, 3) void gemm64_bt(
    const unsigned short* __restrict__ A, const unsigned short* __restrict__ Bt,
    int M, int N, int K, const float* __restrict__ bias,
    const float* __restrict__ res, void* __restrict__ outp) {
    __shared__ __align__(16) unsigned short As[2][64 * 64];
    __shared__ __align__(16) unsigned short Bs[2][64 * 64];
    const int tid = threadIdx.x;
    const int lane = tid & 63, w = tid >> 6;
    const int m0 = blockIdx.y * 64, n0 = blockIdx.x * 64;
    const int quad = lane >> 4, l16 = lane & 15;

    const int r0 = tid >> 3, g0 = tid & 7;           // rows 0..31
    const int r1 = r0 + 32, g1 = g0;                 // rows 32..63
    const unsigned short* gA0 = A  + (size_t)(m0 + r0) * K + g0 * 8;
    const unsigned short* gA1 = A  + (size_t)(m0 + r1) * K + g1 * 8;
    const unsigned short* gB0 = Bt + (size_t)(n0 + r0) * K + g0 * 8;
    const unsigned short* gB1 = Bt + (size_t)(n0 + r1) * K + g1 * 8;
    const int wA0 = r0 * 64 + ((g0 ^ (r0 & 7)) * 8);
    const int wA1 = r1 * 64 + ((g1 ^ (r1 & 7)) * 8);

    f32x4 acc[4];
    const f32x4 z = {0.f, 0.f, 0.f, 0.f};
#pragma unroll
    for (int nt = 0; nt < 4; nt++) acc[nt] = z;

    bf16x8 ra0 = *(const bf16x8*)gA0, ra1 = *(const bf16x8*)gA1;
    bf16x8 rb0 = *(const bf16x8*)gB0, rb1 = *(const bf16x8*)gB1;
    gA0 += 64; gA1 += 64; gB0 += 64; gB1 += 64;

    const int nK = K >> 6;
    for (int kt = 0; kt < nK; ++kt) {
        unsigned short* Ac = As[kt & 1];
        unsigned short* Bc = Bs[kt & 1];
        *(bf16x8*)&Ac[wA0] = ra0; *(bf16x8*)&Ac[wA1] = ra1;
        *(bf16x8*)&Bc[wA0] = rb0; *(bf16x8*)&Bc[wA1] = rb1;
        if (kt + 1 < nK) {
            ra0 = *(const bf16x8*)gA0; ra1 = *(const bf16x8*)gA1;
            rb0 = *(const bf16x8*)gB0; rb1 = *(const bf16x8*)gB1;
            gA0 += 64; gA1 += 64; gB0 += 64; gB1 += 64;
        }
        sync_lds();
        const int ra = 16 * w + l16;
        bf16x8 af0 = *(const bf16x8*)&Ac[ra * 64 + (((0 + quad) ^ (ra & 7)) * 8)];
        bf16x8 af1 = *(const bf16x8*)&Ac[ra * 64 + (((4 + quad) ^ (ra & 7)) * 8)];
#pragma unroll
        for (int nt = 0; nt < 4; nt++) {
            int rb = 16 * nt + l16;
            bf16x8 bf0 = *(const bf16x8*)&Bc[rb * 64 + (((0 + quad) ^ (rb & 7)) * 8)];
            bf16x8 bf1 = *(const bf16x8*)&Bc[rb * 64 + (((4 + quad) ^ (rb & 7)) * 8)];
            acc[nt] = __builtin_amdgcn_mfma_f32_16x16x32_bf16(af0, bf0, acc[nt], 0, 0, 0);
            acc[nt] = __builtin_amdgcn_mfma_f32_16x16x32_bf16(af1, bf1, acc[nt], 0, 0, 0);
        }
    }

#pragma unroll
    for (int nt = 0; nt < 4; nt++) {
        const int col = n0 + 16 * nt + l16;
        float bv = 0.f;
        if (MODE == 1 || MODE == 3) bv = bias[col];
#pragma unroll
        for (int rr = 0; rr < 4; rr++) {
            const int row = m0 + 16 * w + quad * 4 + rr;
            const size_t idx = (size_t)row * N + col;
            const float v = acc[nt][rr];
            if (MODE == 0) ((unsigned short*)outp)[idx] = f2bf(v);
            else if (MODE == 1) ((unsigned short*)outp)[idx] = f2bf(fmaxf(v + bv, 0.f));
            else if (MODE == 2) ((float*)outp)[idx] = v + res[idx];
            else ((float*)outp)[idx] = v + bv + res[idx];
        }
    }
}

// ---------------- V transpose: qkv[.,1536+h*64+dd] -> vt[bh][dd][S] ----------------
__global__ void v_transpose(const unsigned short* __restrict__ qkvc,
                            unsigned short* __restrict__ vt) {
    __shared__ unsigned short t[64][65];
    const int bh = blockIdx.y, b = bh / 12, h = bh % 12;
    const int s0 = blockIdx.x * 64;
    const int tx = threadIdx.x, ty = threadIdx.y;   // 64 x 4
#pragma unroll
    for (int i = 0; i < 64; i += 4)
        t[ty + i][tx] = qkvc[(size_t)(b * 2048 + s0 + ty + i) * 2304 + 1536 + h * 64 + tx];
    __syncthreads();
#pragma unroll
    for (int i = 0; i < 64; i += 4)
        vt[((size_t)bh * 64 + ty + i) * 2048 + s0 + tx] = t[tx][ty + i];
}

// ---------------- flash attention v6: barrier-free k-split, direct global frags -------
// k-split layout (wave w owns k-chunk [w*32,w*32+32) x all 64 q-rows) makes each lane's
// K and V B-fragment 8 CONTIGUOUS elements in global memory (qkvc feature dim / vt S
// dim), with the 4 quads of each l16 covering a full 64B line. So K/V skip LDS entirely:
// direct global->VGPR loads, register-prefetched one iter ahead. Ps is wave-local and
// mask is loaded per-lane => the j-loop has NO barriers; waves run fully independently.
__global__ __launch_bounds__(256, 2) void flash_attn(
    const unsigned short* __restrict__ qkvc,   // [4096][2304] fused q|k|v
    const unsigned short* __restrict__ vt,     // [24][64][2048]
    const int* __restrict__ mask,              // [2][2048]
    unsigned short* __restrict__ attno) {      // [4096][768]
    const int bh = blockIdx.y, b = bh / 12, h = bh % 12;
    const int s0 = blockIdx.x * 64;
    // UQP: Q staging (8KB, pre-loop) / Ps[w][64][40] (20KB, in-loop) / Osc+Lsc (epilogue)
    __shared__ __align__(16) unsigned short UQP[4 * 64 * 40];
    const int tid = threadIdx.x, lane = tid & 63, w = tid >> 6;
    const int quad = lane >> 4, l16 = lane & 15;

    // stage Q tile [64 rows][64 cols] (swizzle g^(r&7)) via async16, once
    {
        int sl0 = (2 * w) * 64 + lane;
        int r0 = sl0 >> 3, g0 = sl0 & 7;
        int sl1 = sl0 + 64;
        int r1 = sl1 >> 3, g1 = sl1 & 7;
        async16(qkvc + (size_t)(b * 2048 + s0 + r0) * 2304 + h * 64 + ((g0 ^ (r0 & 7)) * 8),
                UQP + (2 * w) * 512);
        async16(qkvc + (size_t)(b * 2048 + s0 + r1) * 2304 + h * 64 + ((g1 ^ (r1 & 7)) * 8),
                UQP + (2 * w + 1) * 512);
    }
    __syncthreads();
    // every wave holds Q A-frags for ALL 64 q-rows (4 row-blocks x K=64 dims)
    bf16x8 aQ[4][2];
#pragma unroll
    for (int mt = 0; mt < 4; mt++) {
        int r = 16 * mt + l16;
#pragma unroll
        for (int kk = 0; kk < 2; kk++)
            aQ[mt][kk] = *(const bf16x8*)&UQP[r * 64 + (((kk * 4 + quad) ^ (r & 7)) * 8)];
    }
    __syncthreads();   // all waves done reading Q before any Ps write reuses the region
    __bf16* Ps = (__bf16*)UQP + w * (64 * 40);   // wave-local, rows 16B-aligned

    // direct-global fragment pointers (per lane, 16B contiguous each)
    // K frag (nt,kk): key = k0 + w*32 + nt*16 + l16, dims (kk*4+quad)*8..+7
    const unsigned short* kp0 = qkvc + (size_t)(b * 2048 + w * 32 + l16) * 2304
                                + 768 + h * 64 + quad * 8;          // nt=0 (kk via +32 elems)
    const unsigned short* kp1 = kp0 + (size_t)16 * 2304;            // nt=1
    // V frag (nt): dd = nt*16 + l16, s = k0 + (w*4+quad)*8..+7
    const unsigned short* vp0 = vt + (size_t)bh * 64 * 2048 + (size_t)l16 * 2048
                                + (w * 4 + quad) * 8;               // nt=0
    const unsigned short* vp1 = vp0 + 16 * 2048;
    const unsigned short* vp2 = vp0 + 32 * 2048;
    const unsigned short* vp3 = vp0 + 48 * 2048;
    const int* mp = mask + b * 2048 + w * 32 + l16;

    f32x4 Oacc[4][4], Lacc[4];
    const f32x4 z = {0.f, 0.f, 0.f, 0.f};
#pragma unroll
    for (int mt = 0; mt < 4; mt++) {
        Lacc[mt] = z;
#pragma unroll
        for (int nt = 0; nt < 4; nt++) Oacc[mt][nt] = z;
    }
    bf16x8 ones;
#pragma unroll
    for (int i = 0; i < 8; i++) ones[i] = (__bf16)1.0f;

    const float SCL = 0.125f * 1.44269504088896340736f;   // 1/sqrt(64) * log2(e)
    const float MSK = 1.4426950408889634e-9f;             // 1e-9 * log2(e)

    // prologue: load tile-0 fragments
    bf16x8 ck[2][2], cv[4];
    int cm[2];
    ck[0][0] = *(const bf16x8*)kp0;       ck[0][1] = *(const bf16x8*)(kp0 + 32);
    ck[1][0] = *(const bf16x8*)kp1;       ck[1][1] = *(const bf16x8*)(kp1 + 32);
    cv[0] = *(const bf16x8*)vp0;  cv[1] = *(const bf16x8*)vp1;
    cv[2] = *(const bf16x8*)vp2;  cv[3] = *(const bf16x8*)vp3;
    cm[0] = mp[0];  cm[1] = mp[16];

#pragma unroll 1
    for (int j = 0; j < 16; j++) {
        // prefetch tile j+1 (stays in flight through this iteration's compute)
        bf16x8 nk[2][2], nv[4];
        int nm[2];
        if (j + 1 < 16) {
            kp0 += (size_t)128 * 2304;  kp1 += (size_t)128 * 2304;
            vp0 += 128;  vp1 += 128;  vp2 += 128;  vp3 += 128;  mp += 128;
            nk[0][0] = *(const bf16x8*)kp0;   nk[0][1] = *(const bf16x8*)(kp0 + 32);
            nk[1][0] = *(const bf16x8*)kp1;   nk[1][1] = *(const bf16x8*)(kp1 + 32);
            nv[0] = *(const bf16x8*)vp0;  nv[1] = *(const bf16x8*)vp1;
            nv[2] = *(const bf16x8*)vp2;  nv[3] = *(const bf16x8*)vp3;
            nm[0] = mp[0];  nm[1] = mp[16];
        }

        // per-mt: QK -> exp -> P-write (8 score regs live at a time)
#pragma unroll
        for (int mt = 0; mt < 4; mt++) {
#pragma unroll
            for (int nt = 0; nt < 2; nt++) {
                f32x4 t0 = __builtin_amdgcn_mfma_f32_16x16x32_bf16(aQ[mt][0], ck[nt][0], z, 0, 0, 0);
                f32x4 sc = __builtin_amdgcn_mfma_f32_16x16x32_bf16(aQ[mt][1], ck[nt][1], t0, 0, 0, 0);
                const float fs = cm[nt] ? SCL : 0.f;
                const float ad = cm[nt] ? 0.f : MSK;
#pragma unroll
                for (int r = 0; r < 4; r++)
                    Ps[(mt * 16 + quad * 4 + r) * 40 + nt * 16 + l16] =
                        (__bf16)__builtin_amdgcn_exp2f(fmaf(sc[r], fs, ad));
            }
        }
        // O_w += P_w V[chunk] ; L_w += P_w 1   (K=32 per MFMA, one per (mt,nt))
#pragma unroll
        for (int mt = 0; mt < 4; mt++) {
            bf16x8 aP = *(const bf16x8*)&Ps[(mt * 16 + l16) * 40 + quad * 8];
            Lacc[mt] = __builtin_amdgcn_mfma_f32_16x16x32_bf16(aP, ones, Lacc[mt], 0, 0, 0);
#pragma unroll
            for (int nt = 0; nt < 4; nt++)
                Oacc[mt][nt] = __builtin_amdgcn_mfma_f32_16x16x32_bf16(aP, cv[nt], Oacc[mt][nt], 0, 0, 0);
        }

        // rotate prefetch buffers
        ck[0][0] = nk[0][0]; ck[0][1] = nk[0][1];
        ck[1][0] = nk[1][0]; ck[1][1] = nk[1][1];
        cv[0] = nv[0]; cv[1] = nv[1]; cv[2] = nv[2]; cv[3] = nv[3];
        cm[0] = nm[0]; cm[1] = nm[1];
    }

    // ---- cross-wave reduction of O/L partials (one-time) ----
    __syncthreads();
    float* Osc = (float*)UQP;                       // [4 waves][16 rows][64 cols] = 16KB
    float* Lsc = (float*)((char*)UQP + 16384);      // [4 waves][64 rows] = 1KB
    if (l16 == 0) {
#pragma unroll
        for (int mt = 0; mt < 4; mt++)
#pragma unroll
            for (int r = 0; r < 4; r++)
                Lsc[w * 64 + mt * 16 + quad * 4 + r] = Lacc[mt][r];
    }
#pragma unroll
    for (int mt = 0; mt < 4; mt++) {
#pragma unroll
        for (int nt = 0; nt < 4; nt++)
#pragma unroll
            for (int r = 0; r < 4; r++)
                Osc[(w * 16 + quad * 4 + r) * 64 + nt * 16 + l16] = Oacc[mt][nt][r];
        __syncthreads();
#pragma unroll
        for (int r2 = 0; r2 < 4; r2++) {
            const int lrow = w * 4 + r2;
            float s = Osc[lrow * 64 + lane] + Osc[1024 + lrow * 64 + lane]
                    + Osc[2048 + lrow * 64 + lane] + Osc[3072 + lrow * 64 + lane];
            float L = Lsc[mt * 16 + lrow] + Lsc[64 + mt * 16 + lrow]
                    + Lsc[128 + mt * 16 + lrow] + Lsc[192 + mt * 16 + lrow];
            const int row = s0 + mt * 16 + lrow;
            attno[(size_t)(b * 2048 + row) * 768 + h * 64 + lane] = f2bf(s / L);
        }
        __syncthreads();
    }
}

// =====================================================================================
extern "C" void kernel_launch(void* const* d_in, const int* in_sizes, int n_in,
                              void* d_out, int out_size, void* d_ws, size_t ws_size,
                              hipStream_t stream) {
    const float* x    = (const float*)d_in[0];
    const int*   mask = (const int*)d_in[1];
    const float* wq   = (const float*)d_in[2];
    const float* wk   = (const float*)d_in[3];
    const float* wv   = (const float*)d_in[4];
    const float* wo   = (const float*)d_in[5];
    const float* w1   = (const float*)d_in[6];
    const float* b1   = (const float*)d_in[7];
    const float* w2   = (const float*)d_in[8];
    const float* b2   = (const float*)d_in[9];
    const float* ln1a = (const float*)d_in[10];
    const float* ln1b = (const float*)d_in[11];
    const float* ln2a = (const float*)d_in[12];
    const float* ln2b = (const float*)d_in[13];

    char* p = (char*)d_ws;
    auto carve = [&](size_t bytes) {
        char* q = p;
        p += (bytes + 255) & ~(size_t)255;
        return q;
    };
    unsigned short* wTqkv = (unsigned short*)carve((size_t)2304 * 768 * 2);
    unsigned short* wTo   = (unsigned short*)carve((size_t)768 * 768 * 2);
    unsigned short* wT1   = (unsigned short*)carve((size_t)3072 * 768 * 2);
    unsigned short* wT2   = (unsigned short*)carve((size_t)768 * 3072 * 2);
    unsigned short* vtb   = (unsigned short*)carve((size_t)24 * 64 * 2048 * 2);
    float*          x1    = (float*)carve((size_t)4096 * 768 * 4);
    char* unionA = carve((size_t)4096 * 768 * 2 + (size_t)4096 * 2304 * 2);
    unsigned short* t1   = (unsigned short*)unionA;
    unsigned short* qkvc = (unsigned short*)(unionA + (size_t)4096 * 768 * 2);
    unsigned short* ffnh = (unsigned short*)unionA;
    unsigned short* attno = (unsigned short*)carve((size_t)4096 * 768 * 2);
    unsigned short* t2 = attno;

    dim3 tb(32, 8);
    transpose_cvt<<<dim3(24, 24), tb, 0, stream>>>(wq, wTqkv, 768, 768);
    transpose_cvt<<<dim3(24, 24), tb, 0, stream>>>(wk, wTqkv + (size_t)768 * 768, 768, 768);
    transpose_cvt<<<dim3(24, 24), tb, 0, stream>>>(wv, wTqkv + (size_t)1536 * 768, 768, 768);
    transpose_cvt<<<dim3(24, 24), tb, 0, stream>>>(wo, wTo, 768, 768);
    transpose_cvt<<<dim3(96, 24), tb, 0, stream>>>(w1, wT1, 768, 3072);
    transpose_cvt<<<dim3(24, 96), tb, 0, stream>>>(w2, wT2, 3072, 768);

    ln_kernel<<<4096, 256, 0, stream>>>(x, t1, ln1a, ln1b);
    gemm_bt<0><<<dim3(18, 32), 256, 0, stream>>>(t1, wTqkv, 4096, 2304, 768,
                                                 nullptr, nullptr, qkvc);
    v_transpose<<<dim3(32, 24), dim3(64, 4), 0, stream>>>(qkvc, vtb);
    flash_attn<<<dim3(32, 24), 256, 0, stream>>>(qkvc, vtb, mask, attno);
    gemm64_bt<2><<<dim3(12, 64), 256, 0, stream>>>(attno, wTo, 4096, 768, 768,
                                                   nullptr, x, x1);
    ln_kernel<<<4096, 256, 0, stream>>>(x1, t2, ln2a, ln2b);
    gemm_bt<1><<<dim3(24, 32), 256, 0, stream>>>(t2, wT1, 4096, 3072, 768,
                                                 b1, nullptr, ffnh);
    gemm64_bt<3><<<dim3(12, 64), 256, 0, stream>>>(ffnh, wT2, 4096, 768, 3072,
                                                   b2, x1, (float*)d_out);
}

// Round 9
// 276.327 us; speedup vs baseline: 1.0925x; 1.0483x over previous
//
#include <hip/hip_runtime.h>

typedef float f32x4 __attribute__((ext_vector_type(4)));
typedef __bf16 bf16x8 __attribute__((ext_vector_type(8)));

__device__ __forceinline__ unsigned short f2bf(float f) {
    union { float f; unsigned u; } v; v.f = f;
    unsigned r = v.u + 0x7fffu + ((v.u >> 16) & 1u);
    return (unsigned short)(r >> 16);
}

#define AS1 __attribute__((address_space(1)))
#define AS3 __attribute__((address_space(3)))
// async 16B/lane global->LDS
__device__ __forceinline__ void async16(const void* g, void* l) {
    __builtin_amdgcn_global_load_lds((AS1 void*)g, (AS3 void*)l, 16, 0, 0);
}

// CK-style barrier: orders LDS only (lgkmcnt), leaves global loads (vmcnt) in flight.
__device__ __forceinline__ void sync_lds() {
    asm volatile("s_waitcnt lgkmcnt(0)\n\ts_barrier" ::: "memory");
}

// XOR swizzle for 32-col (4-group) rows
#define SWZ4(r) ((((r) & 3) ^ (((r) >> 2) & 3)))

// ---------------- weight transpose + bf16 convert: W[K][N] -> Wt[N][K] ----------------
__global__ void transpose_cvt(const float* __restrict__ W, unsigned short* __restrict__ Wt,
                              int K, int N) {
    __shared__ float tile[32][33];
    int n0 = blockIdx.x * 32, k0 = blockIdx.y * 32;
    int tx = threadIdx.x, ty = threadIdx.y;
#pragma unroll
    for (int i = 0; i < 32; i += 8)
        tile[ty + i][tx] = W[(size_t)(k0 + ty + i) * N + n0 + tx];
    __syncthreads();
#pragma unroll
    for (int i = 0; i < 32; i += 8)
        Wt[(size_t)(n0 + ty + i) * K + k0 + tx] = f2bf(tile[tx][ty + i]);
}

// ---------------- LayerNorm (ddof=1, /(std+eps)), fp32 in -> bf16 out ----------------
__global__ __launch_bounds__(256) void ln_kernel(const float* __restrict__ x,
                                                 unsigned short* __restrict__ t,
                                                 const float* __restrict__ alpha,
                                                 const float* __restrict__ bias) {
    const int row = blockIdx.x;
    const float* xr = x + (size_t)row * 768;
    float v[3], sum = 0.f, ss = 0.f;
#pragma unroll
    for (int i = 0; i < 3; i++) {
        v[i] = xr[threadIdx.x + 256 * i];
        sum += v[i]; ss += v[i] * v[i];
    }
#pragma unroll
    for (int off = 32; off; off >>= 1) {
        sum += __shfl_down(sum, off);
        ss  += __shfl_down(ss, off);
    }
    __shared__ float s1[4], s2[4];
    int wid = threadIdx.x >> 6, lane = threadIdx.x & 63;
    if (lane == 0) { s1[wid] = sum; s2[wid] = ss; }
    __syncthreads();
    if (threadIdx.x == 0) {
        float a = 0.f, b = 0.f;
#pragma unroll
        for (int i = 0; i < 4; i++) { a += s1[i]; b += s2[i]; }
        s1[0] = a; s2[0] = b;
    }
    __syncthreads();
    sum = s1[0]; ss = s2[0];
    float mean = sum * (1.f / 768.f);
    float var = (ss - sum * mean) * (1.f / 767.f);   // unbiased (ddof=1)
    float sc = alpha[0] / (sqrtf(fmaxf(var, 0.f)) + 1e-6f);
    float bs = bias[0];
#pragma unroll
    for (int i = 0; i < 3; i++)
        t[(size_t)row * 768 + threadIdx.x + 256 * i] = f2bf(sc * (v[i] - mean) + bs);
}

// ---------------- GEMM 128x128, register-prefetch pipelined, BK=32 --------------------
// MODE 0: out bf16 = v              MODE 1: out bf16 = relu(v + bias[col])
// MODE 2: out f32 = v + res         MODE 3: out f32 = v + bias[col] + res
template <int MODE>
__global__ __launch_bounds__(256, 3) void gemm_bt(
    const unsigned short* __restrict__ A, const unsigned short* __restrict__ Bt,
    int M, int N, int K, const float* __restrict__ bias,
    const float* __restrict__ res, void* __restrict__ outp) {
    __shared__ __align__(16) unsigned short As[2][128 * 32];
    __shared__ __align__(16) unsigned short Bs[2][128 * 32];
    const int tid = threadIdx.x;
    const int lane = tid & 63, w = tid >> 6;
    const int wm = w & 1, wn = w >> 1;
    const int m0 = blockIdx.y * 128, n0 = blockIdx.x * 128;
    const int quad = lane >> 4, l16 = lane & 15;

    const int r0 = tid >> 2, g0 = tid & 3;           // rows 0..63
    const int r1 = r0 + 64, g1 = g0;                 // rows 64..127
    const unsigned short* gA0 = A  + (size_t)(m0 + r0) * K + g0 * 8;
    const unsigned short* gA1 = A  + (size_t)(m0 + r1) * K + g1 * 8;
    const unsigned short* gB0 = Bt + (size_t)(n0 + r0) * K + g0 * 8;
    const unsigned short* gB1 = Bt + (size_t)(n0 + r1) * K + g1 * 8;
    const int wA0 = r0 * 32 + ((g0 ^ SWZ4(r0)) * 8);
    const int wA1 = r1 * 32 + ((g1 ^ SWZ4(r1)) * 8);

    f32x4 acc[4][4];
    const f32x4 z = {0.f, 0.f, 0.f, 0.f};
#pragma unroll
    for (int mt = 0; mt < 4; mt++)
#pragma unroll
        for (int nt = 0; nt < 4; nt++) acc[mt][nt] = z;

    bf16x8 ra0 = *(const bf16x8*)gA0, ra1 = *(const bf16x8*)gA1;
    bf16x8 rb0 = *(const bf16x8*)gB0, rb1 = *(const bf16x8*)gB1;
    gA0 += 32; gA1 += 32; gB0 += 32; gB1 += 32;

    const int nK = K >> 5;
    for (int kt = 0; kt < nK; ++kt) {
        unsigned short* Ac = As[kt & 1];
        unsigned short* Bc = Bs[kt & 1];
        *(bf16x8*)&Ac[wA0] = ra0; *(bf16x8*)&Ac[wA1] = ra1;
        *(bf16x8*)&Bc[wA0] = rb0; *(bf16x8*)&Bc[wA1] = rb1;
        if (kt + 1 < nK) {
            ra0 = *(const bf16x8*)gA0; ra1 = *(const bf16x8*)gA1;
            rb0 = *(const bf16x8*)gB0; rb1 = *(const bf16x8*)gB1;
            gA0 += 32; gA1 += 32; gB0 += 32; gB1 += 32;
        }
        sync_lds();
        bf16x8 af[4], bf[4];
#pragma unroll
        for (int mt = 0; mt < 4; mt++) {
            int r = 64 * wm + 16 * mt + l16;
            af[mt] = *(const bf16x8*)&Ac[r * 32 + ((quad ^ SWZ4(r)) * 8)];
        }
#pragma unroll
        for (int nt = 0; nt < 4; nt++) {
            int r = 64 * wn + 16 * nt + l16;
            bf[nt] = *(const bf16x8*)&Bc[r * 32 + ((quad ^ SWZ4(r)) * 8)];
        }
#pragma unroll
        for (int mt = 0; mt < 4; mt++)
#pragma unroll
            for (int nt = 0; nt < 4; nt++)
                acc[mt][nt] = __builtin_amdgcn_mfma_f32_16x16x32_bf16(af[mt], bf[nt], acc[mt][nt], 0, 0, 0);
    }

#pragma unroll
    for (int mt = 0; mt < 4; mt++) {
#pragma unroll
        for (int nt = 0; nt < 4; nt++) {
            const int col = n0 + 64 * wn + 16 * nt + l16;
            float bv = 0.f;
            if (MODE == 1 || MODE == 3) bv = bias[col];
#pragma unroll
            for (int r = 0; r < 4; r++) {
                const int row = m0 + 64 * wm + 16 * mt + quad * 4 + r;
                const size_t idx = (size_t)row * N + col;
                const float v = acc[mt][nt][r];
                if (MODE == 0) ((unsigned short*)outp)[idx] = f2bf(v);
                else if (MODE == 1) ((unsigned short*)outp)[idx] = f2bf(fmaxf(v + bv, 0.f));
                else if (MODE == 2) ((float*)outp)[idx] = v + res[idx];
                else ((float*)outp)[idx] = v + bv + res[idx];
            }
        }
    }
}

// ---------------- GEMM 64x64, register-prefetch pipelined, BK=64 ----------------------
template <int MODE>
__global__ __launch_bounds__(256, 3) void gemm64_bt(
    const unsigned short* __restrict__ A, const unsigned short* __restrict__ Bt,
    int M, int N, int K, const float* __restrict__ bias,
    const float* __restrict__ res, void* __restrict__ outp) {
    __shared__ __align__(16) unsigned short As[2][64 * 64];
    __shared__ __align__(16) unsigned short Bs[2][64 * 64];
    const int tid = threadIdx.x;
    const int lane = tid & 63, w = tid >> 6;
    const int m0 = blockIdx.y * 64, n0 = blockIdx.x * 64;
    const int quad = lane >> 4, l16 = lane & 15;

    const int r0 = tid >> 3, g0 = tid & 7;           // rows 0..31
    const int r1 = r0 + 32, g1 = g0;                 // rows 32..63
    const unsigned short* gA0 = A  + (size_t)(m0 + r0) * K + g0 * 8;
    const unsigned short* gA1 = A  + (size_t)(m0 + r1) * K + g1 * 8;
    const unsigned short* gB0 = Bt + (size_t)(n0 + r0) * K + g0 * 8;
    const unsigned short* gB1 = Bt + (size_t)(n0 + r1) * K + g1 * 8;
    const int wA0 = r0 * 64 + ((g0 ^ (r0 & 7)) * 8);
    const int wA1 = r1 * 64 + ((g1 ^ (r1 & 7)) * 8);

    f32x4 acc[4];
    const f32x4 z = {0.f, 0.f, 0.f, 0.f};
#pragma unroll
    for (int nt = 0; nt < 4; nt++) acc[nt] = z;

    bf16x8 ra0 = *(const bf16x8*)gA0, ra1 = *(const bf16x8*)gA1;
    bf16x8 rb0 = *(const bf16x8*)gB0, rb1 = *(const bf16x8*)gB1;
    gA0 += 64; gA1 += 64; gB0 += 64; gB1 += 64;

    const int nK = K >> 6;
    for (int kt = 0; kt < nK; ++kt) {
        unsigned short* Ac = As[kt & 1];
        unsigned short* Bc = Bs[kt & 1];
        *(bf16x8*)&Ac[wA0] = ra0; *(bf16x8*)&Ac[wA1] = ra1;
        *(bf16x8*)&Bc[wA0] = rb0; *(bf16x8*)&Bc[wA1] = rb1;
        if (kt + 1 < nK) {
            ra0 = *(const bf16x8*)gA0; ra1 = *(const bf16x8*)gA1;
            rb0 = *(const bf16x8*)gB0; rb1 = *(const bf16x8*)gB1;
            gA0 += 64; gA1 += 64; gB0 += 64; gB1 += 64;
        }
        sync_lds();
        const int ra = 16 * w + l16;
        bf16x8 af0 = *(const bf16x8*)&Ac[ra * 64 + (((0 + quad) ^ (ra & 7)) * 8)];
        bf16x8 af1 = *(const bf16x8*)&Ac[ra * 64 + (((4 + quad) ^ (ra & 7)) * 8)];
#pragma unroll
        for (int nt = 0; nt < 4; nt++) {
            int rb = 16 * nt + l16;
            bf16x8 bf0 = *(const bf16x8*)&Bc[rb * 64 + (((0 + quad) ^ (rb & 7)) * 8)];
            bf16x8 bf1 = *(const bf16x8*)&Bc[rb * 64 + (((4 + quad) ^ (rb & 7)) * 8)];
            acc[nt] = __builtin_amdgcn_mfma_f32_16x16x32_bf16(af0, bf0, acc[nt], 0, 0, 0);
            acc[nt] = __builtin_amdgcn_mfma_f32_16x16x32_bf16(af1, bf1, acc[nt], 0, 0, 0);
        }
    }

#pragma unroll
    for (int nt = 0; nt < 4; nt++) {
        const int col = n0 + 16 * nt + l16;
        float bv = 0.f;
        if (MODE == 1 || MODE == 3) bv = bias[col];
#pragma unroll
        for (int rr = 0; rr < 4; rr++) {
            const int row = m0 + 16 * w + quad * 4 + rr;
            const size_t idx = (size_t)row * N + col;
            const float v = acc[nt][rr];
            if (MODE == 0) ((unsigned short*)outp)[idx] = f2bf(v);
            else if (MODE == 1) ((unsigned short*)outp)[idx] = f2bf(fmaxf(v + bv, 0.f));
            else if (MODE == 2) ((float*)outp)[idx] = v + res[idx];
            else ((float*)outp)[idx] = v + bv + res[idx];
        }
    }
}

// ---------------- V transpose: qkv[.,1536+h*64+dd] -> vt[bh][dd][S] ----------------
__global__ void v_transpose(const unsigned short* __restrict__ qkvc,
                            unsigned short* __restrict__ vt) {
    __shared__ unsigned short t[64][65];
    const int bh = blockIdx.y, b = bh / 12, h = bh % 12;
    const int s0 = blockIdx.x * 64;
    const int tx = threadIdx.x, ty = threadIdx.y;   // 64 x 4
#pragma unroll
    for (int i = 0; i < 64; i += 4)
        t[ty + i][tx] = qkvc[(size_t)(b * 2048 + s0 + ty + i) * 2304 + 1536 + h * 64 + tx];
    __syncthreads();
#pragma unroll
    for (int i = 0; i < 64; i += 4)
        vt[((size_t)bh * 64 + ty + i) * 2048 + s0 + tx] = t[tx][ty + i];
}

// ---------------- flash attention v7: 2x2 hybrid q/k split ----------------------------
// Back to the measured-best v2 skeleton (async16 K/V->LDS, 2 barriers/iter, 3 blocks/CU)
// but waves split 2x2: wave (wq=w&1, wk=w>>1) owns 32 q-rows x 64 k-cols. Q stays in
// registers; K/V LDS frag reads drop 32->16 per wave-iter (each frag serves 2x the
// MFMAs vs pure q-split) while Oacc stays at 32 VGPRs (no v4-style spills). Final 2-way
// pair-merge: wk=1 waves publish O/L partials through LDS, wk=0 waves add and store.
__global__ __launch_bounds__(256, 3) void flash_attn(
    const unsigned short* __restrict__ qkvc,   // [4096][2304] fused q|k|v
    const unsigned short* __restrict__ vt,     // [24][64][2048]
    const int* __restrict__ mask,              // [2][2048]
    unsigned short* __restrict__ attno) {      // [4096][768]
    const int bh = blockIdx.y, b = bh / 12, h = bh % 12;
    const int s0 = blockIdx.x * 64;
    __shared__ __align__(16) unsigned short UQP[4 * 32 * 72];  // Qs pre-loop; Ps[w][32][72]
    __shared__ __align__(16) unsigned short Ks[128 * 64];      // fp32 Osc[64][64] in epilogue
    __shared__ __align__(16) unsigned short Vs[64 * 128];      // fp32 Lsc[64] in epilogue
    __shared__ int Ms[128];
    const int tid = threadIdx.x, lane = tid & 63, w = tid >> 6;
    const int quad = lane >> 4, l16 = lane & 15;
    const int wq = w & 1, wk = w >> 1;

    // stage Q tile [64 rows][64 cols] (swizzle g^(r&7)) via async16, once
    {
        int sl0 = (2 * w) * 64 + lane;
        int r0 = sl0 >> 3, g0 = sl0 & 7;
        int sl1 = sl0 + 64;
        int r1 = sl1 >> 3, g1 = sl1 & 7;
        async16(qkvc + (size_t)(b * 2048 + s0 + r0) * 2304 + h * 64 + ((g0 ^ (r0 & 7)) * 8),
                UQP + (2 * w) * 512);
        async16(qkvc + (size_t)(b * 2048 + s0 + r1) * 2304 + h * 64 + ((g1 ^ (r1 & 7)) * 8),
                UQP + (2 * w + 1) * 512);
    }
    __syncthreads();
    // Q A-frags for this wave's 32 q-rows (2 x 16-row blocks, K=64 dims)
    bf16x8 aQ[2][2];
#pragma unroll
    for (int mt = 0; mt < 2; mt++) {
        int r = wq * 32 + mt * 16 + l16;
#pragma unroll
        for (int kk = 0; kk < 2; kk++)
            aQ[mt][kk] = *(const bf16x8*)&UQP[r * 64 + (((kk * 4 + quad) ^ (r & 7)) * 8)];
    }
    __syncthreads();   // all waves done reading Q before Ps overwrites the region
    __bf16* Ps = (__bf16*)UQP + w * (32 * 72);   // wave-local [32 q][stride 72]

    f32x4 Oacc[2][4], Lacc[2];
    const f32x4 z = {0.f, 0.f, 0.f, 0.f};
#pragma unroll
    for (int mt = 0; mt < 2; mt++) {
        Lacc[mt] = z;
#pragma unroll
        for (int nt = 0; nt < 4; nt++) Oacc[mt][nt] = z;
    }
    bf16x8 ones;
#pragma unroll
    for (int i = 0; i < 8; i++) ones[i] = (__bf16)1.0f;

    const unsigned short* kbase = qkvc + 768;
    const unsigned short* vbase = vt + (size_t)bh * 64 * 2048;
    const float SCL = 0.125f * 1.44269504088896340736f;   // 1/sqrt(64) * log2(e)
    const float MSK = 1.4426950408889634e-9f;             // 1e-9 * log2(e)

    for (int j = 0; j < 16; j++) {
        const int k0 = j * 128;
        __syncthreads();
        // stage K tile [128][64] (swizzle g^(r&7)) and V^T tile [64][128] (g^(r&15))
#pragma unroll
        for (int c = 0; c < 4; c++) {
            int sl = (4 * w + c) * 64 + lane;
            int r = sl >> 3, g = sl & 7;
            async16(kbase + (size_t)(b * 2048 + k0 + r) * 2304 + h * 64 + ((g ^ (r & 7)) * 8),
                    Ks + (4 * w + c) * 512);
        }
#pragma unroll
        for (int c = 0; c < 4; c++) {
            int sl = (4 * w + c) * 64 + lane;
            int r = sl >> 4, g = sl & 15;
            async16(vbase + (size_t)r * 2048 + k0 + ((g ^ (r & 15)) * 8),
                    Vs + (4 * w + c) * 512);
        }
        if (tid < 128) Ms[tid] = mask[b * 2048 + k0 + tid];
        __syncthreads();

        // S[32 q][64 k] for this wave's quadrant; K-frags reused across both mt blocks
#pragma unroll
        for (int nt = 0; nt < 4; nt++) {
            const int rr = wk * 64 + nt * 16 + l16;
            bf16x8 bk0 = *(const bf16x8*)&Ks[rr * 64 + (((0 + quad) ^ (rr & 7)) * 8)];
            bf16x8 bk1 = *(const bf16x8*)&Ks[rr * 64 + (((4 + quad) ^ (rr & 7)) * 8)];
            const int msk = Ms[wk * 64 + nt * 16 + l16];
            const float fs = msk ? SCL : 0.f;
            const float ad = msk ? 0.f : MSK;
#pragma unroll
            for (int mt = 0; mt < 2; mt++) {
                f32x4 t0 = __builtin_amdgcn_mfma_f32_16x16x32_bf16(aQ[mt][0], bk0, z, 0, 0, 0);
                f32x4 sc = __builtin_amdgcn_mfma_f32_16x16x32_bf16(aQ[mt][1], bk1, t0, 0, 0, 0);
#pragma unroll
                for (int r = 0; r < 4; r++)
                    Ps[(mt * 16 + quad * 4 + r) * 72 + nt * 16 + l16] =
                        (__bf16)__builtin_amdgcn_exp2f(fmaf(sc[r], fs, ad));
            }
        }

        // O_w += P_w V[64k chunk] ; L_w += P_w 1
#pragma unroll
        for (int kt2 = 0; kt2 < 2; kt2++) {
#pragma unroll
            for (int mt = 0; mt < 2; mt++) {
                bf16x8 aP = *(const bf16x8*)&Ps[(mt * 16 + l16) * 72 + kt2 * 32 + quad * 8];
                Lacc[mt] = __builtin_amdgcn_mfma_f32_16x16x32_bf16(aP, ones, Lacc[mt], 0, 0, 0);
#pragma unroll
                for (int nt = 0; nt < 4; nt++) {
                    const int rr = nt * 16 + l16;
                    bf16x8 bv = *(const bf16x8*)&Vs[rr * 128 +
                                (((wk * 8 + kt2 * 4 + quad) ^ (rr & 15)) * 8)];
                    Oacc[mt][nt] = __builtin_amdgcn_mfma_f32_16x16x32_bf16(aP, bv, Oacc[mt][nt], 0, 0, 0);
                }
            }
        }
    }

    // ---- pair-merge: wk=1 publishes partials, wk=0 adds + stores ----
    __syncthreads();
    float* Osc = (float*)Ks;   // [64 q][64 d] fp32 = 16KB
    float* Lsc = (float*)Vs;   // [64 q] fp32
    if (wk == 1) {
#pragma unroll
        for (int mt = 0; mt < 2; mt++) {
            if (l16 == 0)
#pragma unroll
                for (int r = 0; r < 4; r++)
                    Lsc[wq * 32 + mt * 16 + quad * 4 + r] = Lacc[mt][r];
#pragma unroll
            for (int nt = 0; nt < 4; nt++)
#pragma unroll
                for (int r = 0; r < 4; r++)
                    Osc[(size_t)(wq * 32 + mt * 16 + quad * 4 + r) * 64 + nt * 16 + l16] =
                        Oacc[mt][nt][r];
        }
    }
    __syncthreads();
    if (wk == 0) {
#pragma unroll
        for (int mt = 0; mt < 2; mt++) {
#pragma unroll
            for (int r = 0; r < 4; r++) {
                const int ql = wq * 32 + mt * 16 + quad * 4 + r;
                const float L = Lacc[mt][r] + Lsc[ql];
                const float inv = 1.0f / L;
                const int row = s0 + ql;
#pragma unroll
                for (int nt = 0; nt < 4; nt++) {
                    const float s = Oacc[mt][nt][r] + Osc[(size_t)ql * 64 + nt * 16 + l16];
                    attno[(size_t)(b * 2048 + row) * 768 + h * 64 + nt * 16 + l16] =
                        f2bf(s * inv);
                }
            }
        }
    }
}

// =====================================================================================
extern "C" void kernel_launch(void* const* d_in, const int* in_sizes, int n_in,
                              void* d_out, int out_size, void* d_ws, size_t ws_size,
                              hipStream_t stream) {
    const float* x    = (const float*)d_in[0];
    const int*   mask = (const int*)d_in[1];
    const float* wq   = (const float*)d_in[2];
    const float* wk   = (const float*)d_in[3];
    const float* wv   = (const float*)d_in[4];
    const float* wo   = (const float*)d_in[5];
    const float* w1   = (const float*)d_in[6];
    const float* b1   = (const float*)d_in[7];
    const float* w2   = (const float*)d_in[8];
    const float* b2   = (const float*)d_in[9];
    const float* ln1a = (const float*)d_in[10];
    const float* ln1b = (const float*)d_in[11];
    const float* ln2a = (const float*)d_in[12];
    const float* ln2b = (const float*)d_in[13];

    char* p = (char*)d_ws;
    auto carve = [&](size_t bytes) {
        char* q = p;
        p += (bytes + 255) & ~(size_t)255;
        return q;
    };
    unsigned short* wTqkv = (unsigned short*)carve((size_t)2304 * 768 * 2);
    unsigned short* wTo   = (unsigned short*)carve((size_t)768 * 768 * 2);
    unsigned short* wT1   = (unsigned short*)carve((size_t)3072 * 768 * 2);
    unsigned short* wT2   = (unsigned short*)carve((size_t)768 * 3072 * 2);
    unsigned short* vtb   = (unsigned short*)carve((size_t)24 * 64 * 2048 * 2);
    float*          x1    = (float*)carve((size_t)4096 * 768 * 4);
    char* unionA = carve((size_t)4096 * 768 * 2 + (size_t)4096 * 2304 * 2);
    unsigned short* t1   = (unsigned short*)unionA;
    unsigned short* qkvc = (unsigned short*)(unionA + (size_t)4096 * 768 * 2);
    unsigned short* ffnh = (unsigned short*)unionA;
    unsigned short* attno = (unsigned short*)carve((size_t)4096 * 768 * 2);
    unsigned short* t2 = attno;

    dim3 tb(32, 8);
    transpose_cvt<<<dim3(24, 24), tb, 0, stream>>>(wq, wTqkv, 768, 768);
    transpose_cvt<<<dim3(24, 24), tb, 0, stream>>>(wk, wTqkv + (size_t)768 * 768, 768, 768);
    transpose_cvt<<<dim3(24, 24), tb, 0, stream>>>(wv, wTqkv + (size_t)1536 * 768, 768, 768);
    transpose_cvt<<<dim3(24, 24), tb, 0, stream>>>(wo, wTo, 768, 768);
    transpose_cvt<<<dim3(96, 24), tb, 0, stream>>>(w1, wT1, 768, 3072);
    transpose_cvt<<<dim3(24, 96), tb, 0, stream>>>(w2, wT2, 3072, 768);

    ln_kernel<<<4096, 256, 0, stream>>>(x, t1, ln1a, ln1b);
    gemm_bt<0><<<dim3(18, 32), 256, 0, stream>>>(t1, wTqkv, 4096, 2304, 768,
                                                 nullptr, nullptr, qkvc);
    v_transpose<<<dim3(32, 24), dim3(64, 4), 0, stream>>>(qkvc, vtb);
    flash_attn<<<dim3(32, 24), 256, 0, stream>>>(qkvc, vtb, mask, attno);
    gemm64_bt<2><<<dim3(12, 64), 256, 0, stream>>>(attno, wTo, 4096, 768, 768,
                                                   nullptr, x, x1);
    ln_kernel<<<4096, 256, 0, stream>>>(x1, t2, ln2a, ln2b);
    gemm_bt<1><<<dim3(24, 32), 256, 0, stream>>>(t2, wT1, 4096, 3072, 768,
                                                 b1, nullptr, ffnh);
    gemm64_bt<3><<<dim3(12, 64), 256, 0, stream>>>(ffnh, wT2, 4096, 768, 3072,
                                                   b2, x1, (float*)d_out);
}